// Round 2
// baseline (22804.437 us; speedup 1.0000x reference)
//
#include <hip/hip_runtime.h>
#include <math.h>

#define HH   4
#define NSEQ 1024
#define KVD  960
#define BATCH 8

static constexpr float EPS = 1e-5f;

// ---------------------------------------------------------------------------
// Generic fp32 tiled GEMM core. C[M,Nc] = alpha * sum_{ib} A_ib @ op(B_ib)
//   A: [M,K] row-major (K contiguous)
//   BT=true : B is [Nc,K] row-major (NT pattern, K contiguous)
//   BT=false: B is [K,Nc] row-major (NN pattern)
// Requirements: M,Nc multiples of 64; K multiple of 16. Block = 16x16 threads,
// 64x64 output tile, 4x4 microtile per thread.
// ---------------------------------------------------------------------------
template<bool BT>
__device__ __forceinline__ void gemm_tile(const float* __restrict__ A,
                                          const float* __restrict__ B,
                                          float* __restrict__ C,
                                          int M, int Nc, int K, float alpha,
                                          int innerCount, long strideA, long strideB)
{
    __shared__ float As[16][65];   // [k][m], +1 pad kills store conflicts
    __shared__ float Bs[16][65];   // [k][n]
    const int tx = threadIdx.x, ty = threadIdx.y;
    const int tid = ty * 16 + tx;
    const int m0 = blockIdx.y * 64;
    const int n0 = blockIdx.x * 64;

    float acc[4][4] = {};

    for (int ib = 0; ib < innerCount; ++ib) {
        const float* Ab = A + (long)ib * strideA;
        const float* Bb = B + (long)ib * strideB;
        for (int k0 = 0; k0 < K; k0 += 16) {
            // A tile: As[k][m] = Ab[(m0+m)*K + k0+k]
            {
                const int k = tid & 15;
                const int m = tid >> 4;   // 0..15
                #pragma unroll
                for (int i = 0; i < 4; ++i)
                    As[k][m + 16 * i] = Ab[(long)(m0 + m + 16 * i) * K + k0 + k];
            }
            if (BT) {
                const int k = tid & 15;
                const int n = tid >> 4;
                #pragma unroll
                for (int i = 0; i < 4; ++i)
                    Bs[k][n + 16 * i] = Bb[(long)(n0 + n + 16 * i) * K + k0 + k];
            } else {
                const int n = tid & 63;
                const int k = tid >> 6;   // 0..3
                #pragma unroll
                for (int i = 0; i < 4; ++i)
                    Bs[k + 4 * i][n] = Bb[(long)(k0 + k + 4 * i) * Nc + n0 + n];
            }
            __syncthreads();
            #pragma unroll
            for (int kk = 0; kk < 16; ++kk) {
                float a[4], b[4];
                #pragma unroll
                for (int i = 0; i < 4; ++i) a[i] = As[kk][ty * 4 + i];
                #pragma unroll
                for (int j = 0; j < 4; ++j) b[j] = Bs[kk][tx * 4 + j];
                #pragma unroll
                for (int i = 0; i < 4; ++i)
                    #pragma unroll
                    for (int j = 0; j < 4; ++j)
                        acc[i][j] += a[i] * b[j];
            }
            __syncthreads();
        }
    }

    #pragma unroll
    for (int i = 0; i < 4; ++i) {
        const long m = m0 + ty * 4 + i;
        #pragma unroll
        for (int j = 0; j < 4; ++j)
            C[m * Nc + n0 + tx * 4 + j] = alpha * acc[i][j];
    }
}

// ---- Stage 1 (per batch b): K/V projection for all heads.
// out[h,n,j] = sum_k emb_all[b,n,k] W[h,j,k];  grid (15, 16, H)
__global__ void kv_proj_kernel(const float* __restrict__ emb_all_b,
                               const float* __restrict__ W,
                               float* __restrict__ out)
{
    const int h = blockIdx.z;
    gemm_tile<true>(emb_all_b,
                    W + (long)h * KVD * KVD,
                    out + (long)h * NSEQ * KVD,
                    NSEQ, KVD, KVD, 1.0f, 1, 0, 0);
}

// ---- Stage 2 (per batch b): Q[h,e,n] = sum_d WQ[h,e,d] emb[b,n,d]
// grid (16, df/64, H); Q stored [df, N] row-major per head
__global__ void q_proj_kernel(const float* __restrict__ emb_b,
                              const float* __restrict__ WQ,
                              float* __restrict__ Q, int df)
{
    const int h = blockIdx.z;
    gemm_tile<true>(WQ + (long)h * df * df,
                    emb_b,
                    Q + (long)h * df * NSEQ,
                    df, NSEQ, df, 1.0f, 1, 0, 0);
}

// ---- Stage 3 (per batch b): S[h,e,j] = scale * sum_n Q[h,e,n] K[h,n,j]  (NN)
// grid (15, df/64, H)
__global__ void score_kernel(const float* __restrict__ Q,
                             const float* __restrict__ Kb,
                             float* __restrict__ S, int df, float scale)
{
    const int h = blockIdx.z;
    gemm_tile<false>(Q + (long)h * df * NSEQ,
                     Kb + (long)h * NSEQ * KVD,
                     S + (long)h * df * KVD,
                     df, KVD, NSEQ, scale, 1, 0, 0);
}

// ---- Stage 4 (per batch b): per-h mean / rstd over df*KV. grid (H), block 256
__global__ void stats_kernel(const float* __restrict__ S,
                             float* __restrict__ stats, int df)
{
    const int h = blockIdx.x;
    const float* p = S + (long)h * df * KVD;
    const int n = df * KVD;
    float s = 0.f, ss = 0.f;
    for (int i = threadIdx.x; i < n; i += 256) {
        const float v = p[i];
        s += v; ss += v * v;
    }
    __shared__ float rs[256], rss[256];
    rs[threadIdx.x] = s; rss[threadIdx.x] = ss;
    __syncthreads();
    for (int o = 128; o > 0; o >>= 1) {
        if (threadIdx.x < o) {
            rs[threadIdx.x]  += rs[threadIdx.x + o];
            rss[threadIdx.x] += rss[threadIdx.x + o];
        }
        __syncthreads();
    }
    if (threadIdx.x == 0) {
        const float mean = rs[0] / n;
        const float var  = rss[0] / n - mean * mean;
        stats[2 * h]     = mean;
        stats[2 * h + 1] = rsqrtf(var + EPS);
    }
}

// ---- Stage 5 (per batch b): row softmax of instance-normed scores, in place.
// grid (df, H), block 256; row length KVD=960
__global__ void softmax_kernel(float* __restrict__ S,
                               const float* __restrict__ stats, int df)
{
    const int h = blockIdx.y;
    const float mean = stats[2 * h];
    const float rstd = stats[2 * h + 1];
    float* row = S + (long)h * df * KVD + (long)blockIdx.x * KVD;
    const int t = threadIdx.x;

    float x[4];
    float mx = -1e30f;
    #pragma unroll
    for (int i = 0; i < 4; ++i) {
        const int j = t + i * 256;
        x[i] = (j < KVD) ? (row[j] - mean) * rstd : -1e30f;
        mx = fmaxf(mx, x[i]);
    }
    __shared__ float red[256];
    red[t] = mx; __syncthreads();
    for (int o = 128; o > 0; o >>= 1) {
        if (t < o) red[t] = fmaxf(red[t], red[t + o]);
        __syncthreads();
    }
    mx = red[0];
    __syncthreads();

    float e[4];
    float sum = 0.f;
    #pragma unroll
    for (int i = 0; i < 4; ++i) {
        const int j = t + i * 256;
        e[i] = (j < KVD) ? __expf(x[i] - mx) : 0.f;
        sum += e[i];
    }
    red[t] = sum; __syncthreads();
    for (int o = 128; o > 0; o >>= 1) {
        if (t < o) red[t] += red[t + o];
        __syncthreads();
    }
    const float inv = 1.0f / red[0];
    #pragma unroll
    for (int i = 0; i < 4; ++i) {
        const int j = t + i * 256;
        if (j < KVD) row[j] = e[i] * inv;
    }
}

// ---- Stage 6 (per batch b): Cm[n,e] = (1/H) sum_h sum_j V[h,n,j] A[h,e,j]  (NT)
// grid (df/64, 16, 1)
__global__ void cm_kernel(const float* __restrict__ V,
                          const float* __restrict__ Am,
                          float* __restrict__ Cm, int df)
{
    gemm_tile<true>(V, Am, Cm,
                    NSEQ, df, KVD, 1.0f / HH, HH,
                    (long)NSEQ * KVD, (long)df * KVD);
}

// ---- Stage 7 (per batch b): O[n,f] = sum_e Cm[n,e] WO[f,e]  (NT)
// grid (df/64, 16, 1)
__global__ void out_kernel(const float* __restrict__ Cm,
                           const float* __restrict__ WO,
                           float* __restrict__ Out, int df)
{
    gemm_tile<true>(Cm, WO, Out, NSEQ, df, df, 1.0f, 1, 0, 0);
}

// ---------------------------------------------------------------------------
extern "C" void kernel_launch(void* const* d_in, const int* in_sizes, int n_in,
                              void* d_out, int out_size, void* d_ws, size_t ws_size,
                              hipStream_t stream)
{
    const float* emb[4]  = {(const float*)d_in[0], (const float*)d_in[1],
                            (const float*)d_in[2], (const float*)d_in[3]};
    const float* emb_all = (const float*)d_in[4];
    const float* WQ[4]   = {(const float*)d_in[5], (const float*)d_in[6],
                            (const float*)d_in[7], (const float*)d_in[8]};
    const float* WK      = (const float*)d_in[9];
    const float* WV      = (const float*)d_in[10];
    const float* WO[4]   = {(const float*)d_in[11], (const float*)d_in[12],
                            (const float*)d_in[13], (const float*)d_in[14]};
    float* out = (float*)d_out;
    float* ws  = (float*)d_ws;

    // per-batch workspace layout (floats): total ~12.45M floats ~= 50 MB
    const long szKV = (long)HH * NSEQ * KVD;   // 3,932,160
    const long szQ  = (long)HH * 512 * NSEQ;   // 2,097,152 (max df)
    const long szS  = (long)HH * 512 * KVD;    // 1,966,080 (max df)
    const long szCm = (long)NSEQ * 512;        //   524,288 (max df)
    float* Kbuf  = ws;
    float* Vbuf  = Kbuf + szKV;
    float* Qbuf  = Vbuf + szKV;
    float* Sbuf  = Qbuf + szQ;
    float* Cmbuf = Sbuf + szS;
    float* statsbuf = Cmbuf + szCm;            // 2*H floats

    const dim3 blk(16, 16);
    const float scale = 1.0f / sqrtf((float)KVD);
    const int dfs[4] = {64, 128, 256, 512};
    // output offsets of the 4 branch outputs within d_out (concatenated flat)
    long outBase[4];
    {
        long acc = 0;
        for (int br = 0; br < 4; ++br) { outBase[br] = acc; acc += (long)BATCH * NSEQ * dfs[br]; }
    }

    for (int b = 0; b < BATCH; ++b) {
        const float* emb_all_b = emb_all + (long)b * NSEQ * KVD;
        kv_proj_kernel<<<dim3(KVD / 64, NSEQ / 64, HH), blk, 0, stream>>>(emb_all_b, WK, Kbuf);
        kv_proj_kernel<<<dim3(KVD / 64, NSEQ / 64, HH), blk, 0, stream>>>(emb_all_b, WV, Vbuf);

        for (int br = 0; br < 4; ++br) {
            const int df = dfs[br];
            const float* emb_b = emb[br] + (long)b * NSEQ * df;
            q_proj_kernel<<<dim3(NSEQ / 64, df / 64, HH), blk, 0, stream>>>(emb_b, WQ[br], Qbuf, df);
            score_kernel <<<dim3(KVD / 64, df / 64, HH), blk, 0, stream>>>(Qbuf, Kbuf, Sbuf, df, scale);
            stats_kernel <<<dim3(HH), dim3(256), 0, stream>>>(Sbuf, statsbuf, df);
            softmax_kernel<<<dim3(df, HH), dim3(256), 0, stream>>>(Sbuf, statsbuf, df);
            cm_kernel    <<<dim3(df / 64, NSEQ / 64, 1), blk, 0, stream>>>(Vbuf, Sbuf, Cmbuf, df);
            out_kernel   <<<dim3(df / 64, NSEQ / 64, 1), blk, 0, stream>>>(
                Cmbuf, WO[br], out + outBase[br] + (long)b * NSEQ * df, df);
        }
    }
}

// Round 3
// 15370.291 us; speedup vs baseline: 1.4837x; 1.4837x over previous
//
#include <hip/hip_runtime.h>
#include <math.h>

#define HH   4
#define NSEQ 1024
#define KVD  960
#define BATCH 8
#define SCHUNK 4096   // floats per stats_partial block; df*KVD is always a multiple

static constexpr float EPS = 1e-5f;

// ---------------------------------------------------------------------------
// Generic fp32 tiled GEMM core. C[M,Nc] = alpha * sum_{ib} A_ib @ op(B_ib)
//   A: [M,K] row-major (K contiguous)
//   BT=true : B is [Nc,K] row-major (NT pattern, K contiguous)
//   BT=false: B is [K,Nc] row-major (NN pattern)
// Requirements: M,Nc multiples of 64; K multiple of 16. Block = 16x16 threads,
// 64x64 output tile, 4x4 microtile per thread.
// ---------------------------------------------------------------------------
template<bool BT>
__device__ __forceinline__ void gemm_tile(const float* __restrict__ A,
                                          const float* __restrict__ B,
                                          float* __restrict__ C,
                                          int M, int Nc, int K, float alpha,
                                          int innerCount, long strideA, long strideB)
{
    __shared__ float As[16][65];   // [k][m], +1 pad kills store conflicts
    __shared__ float Bs[16][65];   // [k][n]
    const int tx = threadIdx.x, ty = threadIdx.y;
    const int tid = ty * 16 + tx;
    const int m0 = blockIdx.y * 64;
    const int n0 = blockIdx.x * 64;

    float acc[4][4] = {};

    for (int ib = 0; ib < innerCount; ++ib) {
        const float* Ab = A + (long)ib * strideA;
        const float* Bb = B + (long)ib * strideB;
        for (int k0 = 0; k0 < K; k0 += 16) {
            {
                const int k = tid & 15;
                const int m = tid >> 4;   // 0..15
                #pragma unroll
                for (int i = 0; i < 4; ++i)
                    As[k][m + 16 * i] = Ab[(long)(m0 + m + 16 * i) * K + k0 + k];
            }
            if (BT) {
                const int k = tid & 15;
                const int n = tid >> 4;
                #pragma unroll
                for (int i = 0; i < 4; ++i)
                    Bs[k][n + 16 * i] = Bb[(long)(n0 + n + 16 * i) * K + k0 + k];
            } else {
                const int n = tid & 63;
                const int k = tid >> 6;   // 0..3
                #pragma unroll
                for (int i = 0; i < 4; ++i)
                    Bs[k + 4 * i][n] = Bb[(long)(k0 + k + 4 * i) * Nc + n0 + n];
            }
            __syncthreads();
            #pragma unroll
            for (int kk = 0; kk < 16; ++kk) {
                float a[4], b[4];
                #pragma unroll
                for (int i = 0; i < 4; ++i) a[i] = As[kk][ty * 4 + i];
                #pragma unroll
                for (int j = 0; j < 4; ++j) b[j] = Bs[kk][tx * 4 + j];
                #pragma unroll
                for (int i = 0; i < 4; ++i)
                    #pragma unroll
                    for (int j = 0; j < 4; ++j)
                        acc[i][j] += a[i] * b[j];
            }
            __syncthreads();
        }
    }

    #pragma unroll
    for (int i = 0; i < 4; ++i) {
        const long m = m0 + ty * 4 + i;
        #pragma unroll
        for (int j = 0; j < 4; ++j)
            C[m * Nc + n0 + tx * 4 + j] = alpha * acc[i][j];
    }
}

// ---- Stage 1 (per batch b): K/V projection for all heads.
__global__ void kv_proj_kernel(const float* __restrict__ emb_all_b,
                               const float* __restrict__ W,
                               float* __restrict__ out)
{
    const int h = blockIdx.z;
    gemm_tile<true>(emb_all_b,
                    W + (long)h * KVD * KVD,
                    out + (long)h * NSEQ * KVD,
                    NSEQ, KVD, KVD, 1.0f, 1, 0, 0);
}

// ---- Stage 2 (per batch b): Q[h,e,n] = sum_d WQ[h,e,d] emb[b,n,d]
__global__ void q_proj_kernel(const float* __restrict__ emb_b,
                              const float* __restrict__ WQ,
                              float* __restrict__ Q, int df)
{
    const int h = blockIdx.z;
    gemm_tile<true>(WQ + (long)h * df * df,
                    emb_b,
                    Q + (long)h * df * NSEQ,
                    df, NSEQ, df, 1.0f, 1, 0, 0);
}

// ---- Stage 3 (per batch b): S[h,e,j] = scale * sum_n Q[h,e,n] K[h,n,j]  (NN)
__global__ void score_kernel(const float* __restrict__ Q,
                             const float* __restrict__ Kb,
                             float* __restrict__ S, int df, float scale)
{
    const int h = blockIdx.z;
    gemm_tile<false>(Q + (long)h * df * NSEQ,
                     Kb + (long)h * NSEQ * KVD,
                     S + (long)h * df * KVD,
                     df, KVD, NSEQ, scale, 1, 0, 0);
}

// ---- Stage 4a: partial reduction for instance-norm stats.
// grid (n/SCHUNK, H), block 256. Each block reduces SCHUNK floats -> (sum, sumsq).
__global__ void stats_partial_kernel(const float* __restrict__ S,
                                     float* __restrict__ partial,
                                     int df, int nchunks)
{
    const int h = blockIdx.y;
    const int c = blockIdx.x;
    const float* p = S + (long)h * df * KVD + (long)c * SCHUNK;
    float s = 0.f, ss = 0.f;
    #pragma unroll
    for (int k = 0; k < 4; ++k) {
        const float4 v = *(const float4*)(p + 4 * (threadIdx.x + 256 * k));
        s  += v.x + v.y + v.z + v.w;
        ss += v.x * v.x + v.y * v.y + v.z * v.z + v.w * v.w;
    }
    __shared__ float rs[256], rss[256];
    rs[threadIdx.x] = s; rss[threadIdx.x] = ss;
    __syncthreads();
    for (int o = 128; o > 0; o >>= 1) {
        if (threadIdx.x < o) {
            rs[threadIdx.x]  += rs[threadIdx.x + o];
            rss[threadIdx.x] += rss[threadIdx.x + o];
        }
        __syncthreads();
    }
    if (threadIdx.x == 0) {
        partial[(h * nchunks + c) * 2]     = rs[0];
        partial[(h * nchunks + c) * 2 + 1] = rss[0];
    }
}

// ---- Stage 4b: finalize mean/rstd per head. grid (H), block 128.
__global__ void stats_final_kernel(const float* __restrict__ partial,
                                   float* __restrict__ stats,
                                   int df, int nchunks)
{
    const int h = blockIdx.x;
    const int t = threadIdx.x;
    float s = 0.f, ss = 0.f;
    for (int c = t; c < nchunks; c += 128) {
        s  += partial[(h * nchunks + c) * 2];
        ss += partial[(h * nchunks + c) * 2 + 1];
    }
    __shared__ float rs[128], rss[128];
    rs[t] = s; rss[t] = ss;
    __syncthreads();
    for (int o = 64; o > 0; o >>= 1) {
        if (t < o) { rs[t] += rs[t + o]; rss[t] += rss[t + o]; }
        __syncthreads();
    }
    if (t == 0) {
        const float n = (float)(df * KVD);
        const float mean = rs[0] / n;
        const float var  = rss[0] / n - mean * mean;
        stats[2 * h]     = mean;
        stats[2 * h + 1] = rsqrtf(var + EPS);
    }
}

// ---- Stage 5 (per batch b): row softmax of instance-normed scores, in place.
// grid (df, H), block 256; row length KVD=960
__global__ void softmax_kernel(float* __restrict__ S,
                               const float* __restrict__ stats, int df)
{
    const int h = blockIdx.y;
    const float mean = stats[2 * h];
    const float rstd = stats[2 * h + 1];
    float* row = S + (long)h * df * KVD + (long)blockIdx.x * KVD;
    const int t = threadIdx.x;

    float x[4];
    float mx = -1e30f;
    #pragma unroll
    for (int i = 0; i < 4; ++i) {
        const int j = t + i * 256;
        x[i] = (j < KVD) ? (row[j] - mean) * rstd : -1e30f;
        mx = fmaxf(mx, x[i]);
    }
    __shared__ float red[256];
    red[t] = mx; __syncthreads();
    for (int o = 128; o > 0; o >>= 1) {
        if (t < o) red[t] = fmaxf(red[t], red[t + o]);
        __syncthreads();
    }
    mx = red[0];
    __syncthreads();

    float e[4];
    float sum = 0.f;
    #pragma unroll
    for (int i = 0; i < 4; ++i) {
        const int j = t + i * 256;
        e[i] = (j < KVD) ? __expf(x[i] - mx) : 0.f;
        sum += e[i];
    }
    red[t] = sum; __syncthreads();
    for (int o = 128; o > 0; o >>= 1) {
        if (t < o) red[t] += red[t + o];
        __syncthreads();
    }
    const float inv = 1.0f / red[0];
    #pragma unroll
    for (int i = 0; i < 4; ++i) {
        const int j = t + i * 256;
        if (j < KVD) row[j] = e[i] * inv;
    }
}

// ---- Stage 6 (per batch b): Cm[n,e] = (1/H) sum_h sum_j V[h,n,j] A[h,e,j]  (NT)
__global__ void cm_kernel(const float* __restrict__ V,
                          const float* __restrict__ Am,
                          float* __restrict__ Cm, int df)
{
    gemm_tile<true>(V, Am, Cm,
                    NSEQ, df, KVD, 1.0f / HH, HH,
                    (long)NSEQ * KVD, (long)df * KVD);
}

// ---- Stage 7 (per batch b): O[n,f] = sum_e Cm[n,e] WO[f,e]  (NT)
__global__ void out_kernel(const float* __restrict__ Cm,
                           const float* __restrict__ WO,
                           float* __restrict__ Out, int df)
{
    gemm_tile<true>(Cm, WO, Out, NSEQ, df, df, 1.0f, 1, 0, 0);
}

// ---------------------------------------------------------------------------
extern "C" void kernel_launch(void* const* d_in, const int* in_sizes, int n_in,
                              void* d_out, int out_size, void* d_ws, size_t ws_size,
                              hipStream_t stream)
{
    const float* emb[4]  = {(const float*)d_in[0], (const float*)d_in[1],
                            (const float*)d_in[2], (const float*)d_in[3]};
    const float* emb_all = (const float*)d_in[4];
    const float* WQ[4]   = {(const float*)d_in[5], (const float*)d_in[6],
                            (const float*)d_in[7], (const float*)d_in[8]};
    const float* WK      = (const float*)d_in[9];
    const float* WV      = (const float*)d_in[10];
    const float* WO[4]   = {(const float*)d_in[11], (const float*)d_in[12],
                            (const float*)d_in[13], (const float*)d_in[14]};
    float* out = (float*)d_out;
    float* ws  = (float*)d_ws;

    // per-batch workspace layout (floats): total ~12.45M floats ~= 50 MB
    const long szKV = (long)HH * NSEQ * KVD;   // 3,932,160
    const long szQ  = (long)HH * 512 * NSEQ;   // 2,097,152 (max df)
    const long szS  = (long)HH * 512 * KVD;    // 1,966,080 (max df)
    const long szCm = (long)NSEQ * 512;        //   524,288 (max df)
    float* Kbuf  = ws;
    float* Vbuf  = Kbuf + szKV;
    float* Qbuf  = Vbuf + szKV;
    float* Sbuf  = Qbuf + szQ;
    float* Cmbuf = Sbuf + szS;
    float* statsbuf   = Cmbuf + szCm;          // 2*H floats
    float* partialbuf = statsbuf + 2 * HH;     // up to H*120*2 = 960 floats

    const dim3 blk(16, 16);
    const float scale = 1.0f / sqrtf((float)KVD);
    const int dfs[4] = {64, 128, 256, 512};
    long outBase[4];
    {
        long acc = 0;
        for (int br = 0; br < 4; ++br) { outBase[br] = acc; acc += (long)BATCH * NSEQ * dfs[br]; }
    }

    for (int b = 0; b < BATCH; ++b) {
        const float* emb_all_b = emb_all + (long)b * NSEQ * KVD;
        kv_proj_kernel<<<dim3(KVD / 64, NSEQ / 64, HH), blk, 0, stream>>>(emb_all_b, WK, Kbuf);
        kv_proj_kernel<<<dim3(KVD / 64, NSEQ / 64, HH), blk, 0, stream>>>(emb_all_b, WV, Vbuf);

        for (int br = 0; br < 4; ++br) {
            const int df = dfs[br];
            const int nchunks = df * KVD / SCHUNK;   // exact: df*960 % 4096 == 0
            const float* emb_b = emb[br] + (long)b * NSEQ * df;
            q_proj_kernel<<<dim3(NSEQ / 64, df / 64, HH), blk, 0, stream>>>(emb_b, WQ[br], Qbuf, df);
            score_kernel <<<dim3(KVD / 64, df / 64, HH), blk, 0, stream>>>(Qbuf, Kbuf, Sbuf, df, scale);
            stats_partial_kernel<<<dim3(nchunks, HH), dim3(256), 0, stream>>>(Sbuf, partialbuf, df, nchunks);
            stats_final_kernel  <<<dim3(HH), dim3(128), 0, stream>>>(partialbuf, statsbuf, df, nchunks);
            softmax_kernel<<<dim3(df, HH), dim3(256), 0, stream>>>(Sbuf, statsbuf, df);
            cm_kernel    <<<dim3(df / 64, NSEQ / 64, 1), blk, 0, stream>>>(Vbuf, Sbuf, Cmbuf, df);
            out_kernel   <<<dim3(df / 64, NSEQ / 64, 1), blk, 0, stream>>>(
                Cmbuf, WO[br], out + outBase[br] + (long)b * NSEQ * df, df);
        }
    }
}

// Round 4
// 5583.482 us; speedup vs baseline: 4.0843x; 2.7528x over previous
//
#include <hip/hip_runtime.h>
#include <hip/hip_bf16.h>
#include <math.h>

#define HH   4
#define NSEQ 1024
#define KVD  960
#define BATCH 8
#define SCHUNK 4096   // floats per stats_partial block; df*KVD is always a multiple

static constexpr float EPS = 1e-5f;

typedef __attribute__((ext_vector_type(8))) short short8;   // 8 bf16 = 4 VGPRs (MFMA A/B frag)
typedef __attribute__((ext_vector_type(4))) float f32x4;    // MFMA C/D frag

__device__ __forceinline__ short f2bf(float x) {
    union { __hip_bfloat16 h; short s; } u;
    u.h = __float2bfloat16(x);
    return u.s;
}

// Stage a ROWS x 32 fp32 tile (row stride ld) into LDS as bf16, rows padded to 40.
// 256 threads: 4 threads/row x 8 cols each; ROWS/64 passes.
template<int ROWS>
__device__ __forceinline__ void stage_tile(short (*dst)[40], const float* __restrict__ src,
                                           int ld, int tid)
{
    #pragma unroll
    for (int p = 0; p < ROWS / 64; ++p) {
        const int row = p * 64 + (tid >> 2);
        const int c8  = (tid & 3) * 8;
        const float* g = src + (long)row * ld + c8;
        const float4 v0 = *(const float4*)g;
        const float4 v1 = *(const float4*)(g + 4);
        short8 t;
        t[0] = f2bf(v0.x); t[1] = f2bf(v0.y); t[2] = f2bf(v0.z); t[3] = f2bf(v0.w);
        t[4] = f2bf(v1.x); t[5] = f2bf(v1.y); t[6] = f2bf(v1.z); t[7] = f2bf(v1.w);
        *(short8*)&dst[row][c8] = t;   // 16B aligned: row*80 + c8*2, 80 = 5*16
    }
}

// ---------------------------------------------------------------------------
// bf16-MFMA NT GEMM: C[M,Nc] = alpha * sum_ib A_ib[M,K] @ B_ib[Nc,K]^T
// (both operands K-contiguous). Block = 256 threads = 4 waves in a 2x2 grid;
// each wave computes a (TM/2)x(TN/2) quadrant via 16x16x32 bf16 MFMA.
// grid = (Nc/TN, M/TM, Z); per-Z offsets zA/zB/zC; inner-loop (h) accumulate
// via inner/sA/sB. Requires M%TM==0, Nc%TN==0, K%32==0.
// ---------------------------------------------------------------------------
template<int TM, int TN>
__global__ __launch_bounds__(256) void mfma_nt_kernel(
    const float* __restrict__ A, const float* __restrict__ B, float* __restrict__ C,
    int lda, int ldb, int ldc, int K, float alpha,
    int inner, long sA, long sB, long zA, long zB, long zC)
{
    constexpr int MT = TM / 32;   // 16-row MFMA tiles per wave (m-dir)
    constexpr int NT = TN / 32;   // 16-col MFMA tiles per wave (n-dir)
    __shared__ short As[TM][40];
    __shared__ short Bs[TN][40];

    A += (long)blockIdx.z * zA;
    B += (long)blockIdx.z * zB;
    C += (long)blockIdx.z * zC;

    const int tid  = threadIdx.x;
    const int lane = tid & 63;
    const int w    = tid >> 6;
    const int wr   = w >> 1;         // wave row-half
    const int wc   = w & 1;          // wave col-half
    const int quad = lane >> 4;
    const int l16  = lane & 15;
    const long m0  = (long)blockIdx.y * TM;
    const long n0  = (long)blockIdx.x * TN;

    f32x4 acc[MT][NT];
    #pragma unroll
    for (int i = 0; i < MT; ++i)
        #pragma unroll
        for (int j = 0; j < NT; ++j)
            acc[i][j] = (f32x4){0.f, 0.f, 0.f, 0.f};

    for (int ib = 0; ib < inner; ++ib) {
        const float* Ab = A + (long)ib * sA + m0 * lda;
        const float* Bb = B + (long)ib * sB + n0 * ldb;
        for (int k0 = 0; k0 < K; k0 += 32) {
            stage_tile<TM>(As, Ab + k0, lda, tid);
            stage_tile<TN>(Bs, Bb + k0, ldb, tid);
            __syncthreads();
            short8 af[MT], bfr[NT];
            #pragma unroll
            for (int i = 0; i < MT; ++i)
                af[i] = *(const short8*)&As[wr * (TM / 2) + i * 16 + l16][quad * 8];
            #pragma unroll
            for (int j = 0; j < NT; ++j)
                bfr[j] = *(const short8*)&Bs[wc * (TN / 2) + j * 16 + l16][quad * 8];
            #pragma unroll
            for (int i = 0; i < MT; ++i)
                #pragma unroll
                for (int j = 0; j < NT; ++j)
                    acc[i][j] = __builtin_amdgcn_mfma_f32_16x16x32_bf16(
                        af[i], bfr[j], acc[i][j], 0, 0, 0);
            __syncthreads();
        }
    }

    // C/D layout: col = lane&15, row = (lane>>4)*4 + reg   [m89-verified]
    #pragma unroll
    for (int i = 0; i < MT; ++i) {
        #pragma unroll
        for (int j = 0; j < NT; ++j) {
            const long row = m0 + wr * (TM / 2) + i * 16 + quad * 4;
            const long col = n0 + wc * (TN / 2) + j * 16 + l16;
            #pragma unroll
            for (int r = 0; r < 4; ++r)
                C[(row + r) * ldc + col] = alpha * acc[i][j][r];
        }
    }
}

// ---- Stage 4a: partial reduction for instance-norm stats.
__global__ void stats_partial_kernel(const float* __restrict__ S,
                                     float* __restrict__ partial,
                                     int df, int nchunks)
{
    const int h = blockIdx.y;
    const int c = blockIdx.x;
    const float* p = S + (long)h * df * KVD + (long)c * SCHUNK;
    float s = 0.f, ss = 0.f;
    #pragma unroll
    for (int k = 0; k < 4; ++k) {
        const float4 v = *(const float4*)(p + 4 * (threadIdx.x + 256 * k));
        s  += v.x + v.y + v.z + v.w;
        ss += v.x * v.x + v.y * v.y + v.z * v.z + v.w * v.w;
    }
    __shared__ float rs[256], rss[256];
    rs[threadIdx.x] = s; rss[threadIdx.x] = ss;
    __syncthreads();
    for (int o = 128; o > 0; o >>= 1) {
        if (threadIdx.x < o) {
            rs[threadIdx.x]  += rs[threadIdx.x + o];
            rss[threadIdx.x] += rss[threadIdx.x + o];
        }
        __syncthreads();
    }
    if (threadIdx.x == 0) {
        partial[(h * nchunks + c) * 2]     = rs[0];
        partial[(h * nchunks + c) * 2 + 1] = rss[0];
    }
}

// ---- Stage 4b: finalize mean/rstd per head.
__global__ void stats_final_kernel(const float* __restrict__ partial,
                                   float* __restrict__ stats,
                                   int df, int nchunks)
{
    const int h = blockIdx.x;
    const int t = threadIdx.x;
    float s = 0.f, ss = 0.f;
    for (int c = t; c < nchunks; c += 128) {
        s  += partial[(h * nchunks + c) * 2];
        ss += partial[(h * nchunks + c) * 2 + 1];
    }
    __shared__ float rs[128], rss[128];
    rs[t] = s; rss[t] = ss;
    __syncthreads();
    for (int o = 64; o > 0; o >>= 1) {
        if (t < o) { rs[t] += rs[t + o]; rss[t] += rss[t + o]; }
        __syncthreads();
    }
    if (t == 0) {
        const float n = (float)(df * KVD);
        const float mean = rs[0] / n;
        const float var  = rss[0] / n - mean * mean;
        stats[2 * h]     = mean;
        stats[2 * h + 1] = rsqrtf(var + EPS);
    }
}

// ---- Stage 5: row softmax of instance-normed scores, in place.
__global__ void softmax_kernel(float* __restrict__ S,
                               const float* __restrict__ stats, int df)
{
    const int h = blockIdx.y;
    const float mean = stats[2 * h];
    const float rstd = stats[2 * h + 1];
    float* row = S + (long)h * df * KVD + (long)blockIdx.x * KVD;
    const int t = threadIdx.x;

    float x[4];
    float mx = -1e30f;
    #pragma unroll
    for (int i = 0; i < 4; ++i) {
        const int j = t + i * 256;
        x[i] = (j < KVD) ? (row[j] - mean) * rstd : -1e30f;
        mx = fmaxf(mx, x[i]);
    }
    __shared__ float red[256];
    red[t] = mx; __syncthreads();
    for (int o = 128; o > 0; o >>= 1) {
        if (t < o) red[t] = fmaxf(red[t], red[t + o]);
        __syncthreads();
    }
    mx = red[0];
    __syncthreads();

    float e[4];
    float sum = 0.f;
    #pragma unroll
    for (int i = 0; i < 4; ++i) {
        const int j = t + i * 256;
        e[i] = (j < KVD) ? __expf(x[i] - mx) : 0.f;
        sum += e[i];
    }
    red[t] = sum; __syncthreads();
    for (int o = 128; o > 0; o >>= 1) {
        if (t < o) red[t] += red[t + o];
        __syncthreads();
    }
    const float inv = 1.0f / red[0];
    #pragma unroll
    for (int i = 0; i < 4; ++i) {
        const int j = t + i * 256;
        if (j < KVD) row[j] = e[i] * inv;
    }
}

// ---------------------------------------------------------------------------
extern "C" void kernel_launch(void* const* d_in, const int* in_sizes, int n_in,
                              void* d_out, int out_size, void* d_ws, size_t ws_size,
                              hipStream_t stream)
{
    const float* emb[4]  = {(const float*)d_in[0], (const float*)d_in[1],
                            (const float*)d_in[2], (const float*)d_in[3]};
    const float* emb_all = (const float*)d_in[4];
    const float* WQ[4]   = {(const float*)d_in[5], (const float*)d_in[6],
                            (const float*)d_in[7], (const float*)d_in[8]};
    const float* WK      = (const float*)d_in[9];
    const float* WV      = (const float*)d_in[10];
    const float* WO[4]   = {(const float*)d_in[11], (const float*)d_in[12],
                            (const float*)d_in[13], (const float*)d_in[14]};
    float* out = (float*)d_out;
    float* ws  = (float*)d_ws;

    // per-batch workspace layout (floats): ~50 MB
    const long szKV = (long)HH * NSEQ * KVD;   // 3,932,160
    const long szQ  = (long)HH * 512 * NSEQ;   // 2,097,152 (max df)
    const long szS  = (long)HH * 512 * KVD;    // 1,966,080 (max df)
    const long szCm = (long)NSEQ * 512;        //   524,288 (max df)
    float* KTbuf = ws;                         // KT[h][j][n]  (transposed K!)
    float* Vbuf  = KTbuf + szKV;               // V[h][n][j]
    float* Qbuf  = Vbuf + szKV;                // Q[h][e][n]
    float* Sbuf  = Qbuf + szQ;                 // S[h][e][j]
    float* Cmbuf = Sbuf + szS;                 // Cm[n][e]
    float* statsbuf   = Cmbuf + szCm;          // 2*H floats
    float* partialbuf = statsbuf + 2 * HH;     // up to H*120*2 floats

    const float scale = 1.0f / sqrtf((float)KVD);
    const int dfs[4] = {64, 128, 256, 512};
    long outBase[4];
    {
        long acc = 0;
        for (int br = 0; br < 4; ++br) { outBase[br] = acc; acc += (long)BATCH * NSEQ * dfs[br]; }
    }

    const dim3 blk(256);
    for (int b = 0; b < BATCH; ++b) {
        const float* emb_all_b = emb_all + (long)b * NSEQ * KVD;

        // KT[h][j][n] = sum_k WK[h][j][k] * emb_all[b][n][k]   (M=KVD, Nc=NSEQ, K=KVD)
        mfma_nt_kernel<64, 128><<<dim3(NSEQ / 128, KVD / 64, HH), blk, 0, stream>>>(
            WK, emb_all_b, KTbuf, KVD, KVD, NSEQ, KVD, 1.0f,
            1, 0, 0, (long)KVD * KVD, 0, (long)KVD * NSEQ);

        // V[h][n][j] = sum_k emb_all[b][n][k] * WV[h][j][k]    (M=NSEQ, Nc=KVD, K=KVD)
        mfma_nt_kernel<128, 64><<<dim3(KVD / 64, NSEQ / 128, HH), blk, 0, stream>>>(
            emb_all_b, WV, Vbuf, KVD, KVD, KVD, KVD, 1.0f,
            1, 0, 0, 0, (long)KVD * KVD, (long)NSEQ * KVD);

        for (int br = 0; br < 4; ++br) {
            const int df = dfs[br];
            const int nchunks = df * KVD / SCHUNK;
            const float* emb_b = emb[br] + (long)b * NSEQ * df;

            // Q[h][e][n] = sum_d WQ[h][e][d] * emb[b][n][d]    (M=df, Nc=NSEQ, K=df)
            mfma_nt_kernel<64, 128><<<dim3(NSEQ / 128, df / 64, HH), blk, 0, stream>>>(
                WQ[br], emb_b, Qbuf, df, df, NSEQ, df, 1.0f,
                1, 0, 0, (long)df * df, 0, (long)df * NSEQ);

            // S[h][e][j] = scale * sum_n Q[h][e][n] * KT[h][j][n]  (M=df, Nc=KVD, K=NSEQ)
            if (df % 128 == 0) {
                mfma_nt_kernel<128, 64><<<dim3(KVD / 64, df / 128, HH), blk, 0, stream>>>(
                    Qbuf, KTbuf, Sbuf, NSEQ, NSEQ, KVD, NSEQ, scale,
                    1, 0, 0, (long)df * NSEQ, (long)KVD * NSEQ, (long)df * KVD);
            } else {
                mfma_nt_kernel<64, 64><<<dim3(KVD / 64, df / 64, HH), blk, 0, stream>>>(
                    Qbuf, KTbuf, Sbuf, NSEQ, NSEQ, KVD, NSEQ, scale,
                    1, 0, 0, (long)df * NSEQ, (long)KVD * NSEQ, (long)df * KVD);
            }

            stats_partial_kernel<<<dim3(nchunks, HH), dim3(256), 0, stream>>>(Sbuf, partialbuf, df, nchunks);
            stats_final_kernel  <<<dim3(HH), dim3(128), 0, stream>>>(partialbuf, statsbuf, df, nchunks);
            softmax_kernel<<<dim3(df, HH), dim3(256), 0, stream>>>(Sbuf, statsbuf, df);

            // Cm[n][e] = (1/H) sum_h sum_j V[h][n][j] * A[h][e][j]  (M=NSEQ, Nc=df, K=KVD)
            mfma_nt_kernel<128, 64><<<dim3(df / 64, NSEQ / 128, 1), blk, 0, stream>>>(
                Vbuf, Sbuf, Cmbuf, KVD, KVD, df, KVD, 1.0f / HH,
                HH, (long)NSEQ * KVD, (long)df * KVD, 0, 0, 0);

            // O[n][f] = sum_e Cm[n][e] * WO[f][e]                  (M=NSEQ, Nc=df, K=df)
            mfma_nt_kernel<128, 64><<<dim3(df / 64, NSEQ / 128, 1), blk, 0, stream>>>(
                Cmbuf, WO[br], out + outBase[br] + (long)b * NSEQ * df, df, df, df, df, 1.0f,
                1, 0, 0, 0, 0, 0);
        }
    }
}

// Round 5
// 1243.174 us; speedup vs baseline: 18.3437x; 4.4913x over previous
//
#include <hip/hip_runtime.h>
#include <hip/hip_bf16.h>
#include <math.h>

#define HH   4
#define NSEQ 1024
#define KVD  960
#define BATCH 8
#define SCHUNK 4096   // floats per stats_partial block; df*KVD is always a multiple

static constexpr float EPS = 1e-5f;

typedef __attribute__((ext_vector_type(8))) short short8;   // 8 bf16 (MFMA A/B frag)
typedef __attribute__((ext_vector_type(4))) float f32x4;    // MFMA C/D frag

__device__ __forceinline__ short f2bf(float x) {
    union { __hip_bfloat16 h; short s; } u;
    u.h = __float2bfloat16(x);
    return u.s;
}

// Stage a ROWS x 32 tile (row stride ld, source fp32 or bf16) into LDS bf16,
// rows padded to 40 shorts (80 B = 16B-aligned rows, 20-bank advance).
// 256 threads: 4 threads/row x 8 cols; ROWS/64 passes.
template<int ROWS, typename T>
__device__ __forceinline__ void stage_tile(short (*dst)[40], const T* __restrict__ src,
                                           int ld, int tid)
{
    #pragma unroll
    for (int p = 0; p < ROWS / 64; ++p) {
        const int row = p * 64 + (tid >> 2);
        const int c8  = (tid & 3) * 8;
        if constexpr (sizeof(T) == 4) {   // fp32 source -> convert
            const float* g = (const float*)src + (long)row * ld + c8;
            const float4 v0 = *(const float4*)g;
            const float4 v1 = *(const float4*)(g + 4);
            short8 t;
            t[0] = f2bf(v0.x); t[1] = f2bf(v0.y); t[2] = f2bf(v0.z); t[3] = f2bf(v0.w);
            t[4] = f2bf(v1.x); t[5] = f2bf(v1.y); t[6] = f2bf(v1.z); t[7] = f2bf(v1.w);
            *(short8*)&dst[row][c8] = t;
        } else {                          // bf16 source -> copy
            const short* g = (const short*)src + (long)row * ld + c8;
            *(short8*)&dst[row][c8] = *(const short8*)g;
        }
    }
}

// ---------------------------------------------------------------------------
// bf16-MFMA NT GEMM: C[M,Nc] = alpha * sum_ib A_ib[M,K] @ B_ib[Nc,K]^T
// (both operands K-contiguous; fp32 sources converted during staging).
// Block = 256 threads = 4 waves (2x2); wave computes (TM/2)x(TN/2) quadrant.
// grid = (Nc/TN, M/TM, Z). Z decomposes as z = g*HH + h when splitH, else g=z.
// Per-(h,g) base offsets zAh/zAg/..., inner-loop (e.g. head sum) via
// inner/sA/sB. Requires M%TM==0, Nc%TN==0, K%32==0.
// ---------------------------------------------------------------------------
template<int TM, int TN, typename TA, typename TB, typename TC>
__global__ __launch_bounds__(256) void mfma_nt(
    const TA* __restrict__ A, const TB* __restrict__ B, TC* __restrict__ C,
    int lda, int ldb, int ldc, int K, float alpha, int inner, long sA, long sB,
    long zAh, long zAg, long zBh, long zBg, long zCh, long zCg, int splitH)
{
    constexpr int MT = TM / 32;
    constexpr int NT = TN / 32;
    __shared__ short As[TM][40];
    __shared__ short Bs[TN][40];

    int h, g;
    if (splitH) { h = blockIdx.z & (HH - 1); g = blockIdx.z >> 2; }
    else        { h = 0;                     g = blockIdx.z; }
    A += (long)h * zAh + (long)g * zAg;
    B += (long)h * zBh + (long)g * zBg;
    C += (long)h * zCh + (long)g * zCg;

    const int tid  = threadIdx.x;
    const int lane = tid & 63;
    const int w    = tid >> 6;
    const int wr   = w >> 1;
    const int wc   = w & 1;
    const int quad = lane >> 4;
    const int l16  = lane & 15;
    const long m0  = (long)blockIdx.y * TM;
    const long n0  = (long)blockIdx.x * TN;

    f32x4 acc[MT][NT];
    #pragma unroll
    for (int i = 0; i < MT; ++i)
        #pragma unroll
        for (int j = 0; j < NT; ++j)
            acc[i][j] = (f32x4){0.f, 0.f, 0.f, 0.f};

    for (int ib = 0; ib < inner; ++ib) {
        const TA* Ab = A + (long)ib * sA + m0 * lda;
        const TB* Bb = B + (long)ib * sB + n0 * ldb;
        for (int k0 = 0; k0 < K; k0 += 32) {
            stage_tile<TM>(As, Ab + k0, lda, tid);
            stage_tile<TN>(Bs, Bb + k0, ldb, tid);
            __syncthreads();
            short8 af[MT], bfr[NT];
            #pragma unroll
            for (int i = 0; i < MT; ++i)
                af[i] = *(const short8*)&As[wr * (TM / 2) + i * 16 + l16][quad * 8];
            #pragma unroll
            for (int j = 0; j < NT; ++j)
                bfr[j] = *(const short8*)&Bs[wc * (TN / 2) + j * 16 + l16][quad * 8];
            #pragma unroll
            for (int i = 0; i < MT; ++i)
                #pragma unroll
                for (int j = 0; j < NT; ++j)
                    acc[i][j] = __builtin_amdgcn_mfma_f32_16x16x32_bf16(
                        af[i], bfr[j], acc[i][j], 0, 0, 0);
            __syncthreads();
        }
    }

    // C/D layout: col = lane&15, row = (lane>>4)*4 + reg   [m89-verified]
    #pragma unroll
    for (int i = 0; i < MT; ++i) {
        #pragma unroll
        for (int j = 0; j < NT; ++j) {
            const long row = m0 + wr * (TM / 2) + i * 16 + quad * 4;
            const long col = n0 + wc * (TN / 2) + j * 16 + l16;
            #pragma unroll
            for (int r = 0; r < 4; ++r) {
                const float v = alpha * acc[i][j][r];
                if constexpr (sizeof(TC) == 4)
                    C[(row + r) * ldc + col] = v;
                else
                    C[(row + r) * ldc + col] = f2bf(v);
            }
        }
    }
}

// ---- instance-norm stats, phase 1: grid (nchunks, G*H), block 256
__global__ void stats_partial_kernel(const float* __restrict__ S,
                                     float* __restrict__ partial,
                                     int df, int nchunks)
{
    const int y = blockIdx.y;            // g*HH + h
    const int c = blockIdx.x;
    const float* p = S + (long)y * df * KVD + (long)c * SCHUNK;
    float s = 0.f, ss = 0.f;
    #pragma unroll
    for (int k = 0; k < 4; ++k) {
        const float4 v = *(const float4*)(p + 4 * (threadIdx.x + 256 * k));
        s  += v.x + v.y + v.z + v.w;
        ss += v.x * v.x + v.y * v.y + v.z * v.z + v.w * v.w;
    }
    __shared__ float rs[256], rss[256];
    rs[threadIdx.x] = s; rss[threadIdx.x] = ss;
    __syncthreads();
    for (int o = 128; o > 0; o >>= 1) {
        if (threadIdx.x < o) {
            rs[threadIdx.x]  += rs[threadIdx.x + o];
            rss[threadIdx.x] += rss[threadIdx.x + o];
        }
        __syncthreads();
    }
    if (threadIdx.x == 0) {
        partial[((long)y * nchunks + c) * 2]     = rs[0];
        partial[((long)y * nchunks + c) * 2 + 1] = rss[0];
    }
}

// ---- stats phase 2: grid (G*H), block 128
__global__ void stats_final_kernel(const float* __restrict__ partial,
                                   float* __restrict__ stats,
                                   int df, int nchunks)
{
    const int y = blockIdx.x;
    const int t = threadIdx.x;
    float s = 0.f, ss = 0.f;
    for (int c = t; c < nchunks; c += 128) {
        s  += partial[((long)y * nchunks + c) * 2];
        ss += partial[((long)y * nchunks + c) * 2 + 1];
    }
    __shared__ float rs[128], rss[128];
    rs[t] = s; rss[t] = ss;
    __syncthreads();
    for (int o = 64; o > 0; o >>= 1) {
        if (t < o) { rs[t] += rs[t + o]; rss[t] += rss[t + o]; }
        __syncthreads();
    }
    if (t == 0) {
        const float n = (float)(df * KVD);
        const float mean = rs[0] / n;
        const float var  = rss[0] / n - mean * mean;
        stats[2 * y]     = mean;
        stats[2 * y + 1] = rsqrtf(var + EPS);
    }
}

// ---- row softmax of instance-normed scores, in place. grid (df, G*H), block 256
__global__ void softmax_kernel(float* __restrict__ S,
                               const float* __restrict__ stats, int df)
{
    const int y = blockIdx.y;
    const float mean = stats[2 * y];
    const float rstd = stats[2 * y + 1];
    float* row = S + (long)y * df * KVD + (long)blockIdx.x * KVD;
    const int t = threadIdx.x;

    float x[4];
    float mx = -1e30f;
    #pragma unroll
    for (int i = 0; i < 4; ++i) {
        const int j = t + i * 256;
        x[i] = (j < KVD) ? (row[j] - mean) * rstd : -1e30f;
        mx = fmaxf(mx, x[i]);
    }
    __shared__ float red[256];
    red[t] = mx; __syncthreads();
    for (int o = 128; o > 0; o >>= 1) {
        if (t < o) red[t] = fmaxf(red[t], red[t + o]);
        __syncthreads();
    }
    mx = red[0];
    __syncthreads();

    float e[4];
    float sum = 0.f;
    #pragma unroll
    for (int i = 0; i < 4; ++i) {
        const int j = t + i * 256;
        e[i] = (j < KVD) ? __expf(x[i] - mx) : 0.f;
        sum += e[i];
    }
    red[t] = sum; __syncthreads();
    for (int o = 128; o > 0; o >>= 1) {
        if (t < o) red[t] += red[t + o];
        __syncthreads();
    }
    const float inv = 1.0f / red[0];
    #pragma unroll
    for (int i = 0; i < 4; ++i) {
        const int j = t + i * 256;
        if (j < KVD) row[j] = e[i] * inv;
    }
}

// ---------------------------------------------------------------------------
extern "C" void kernel_launch(void* const* d_in, const int* in_sizes, int n_in,
                              void* d_out, int out_size, void* d_ws, size_t ws_size,
                              hipStream_t stream)
{
    const float* emb[4]  = {(const float*)d_in[0], (const float*)d_in[1],
                            (const float*)d_in[2], (const float*)d_in[3]};
    const float* emb_all = (const float*)d_in[4];
    const float* WQ[4]   = {(const float*)d_in[5], (const float*)d_in[6],
                            (const float*)d_in[7], (const float*)d_in[8]};
    const float* WK      = (const float*)d_in[9];
    const float* WV      = (const float*)d_in[10];
    const float* WO[4]   = {(const float*)d_in[11], (const float*)d_in[12],
                            (const float*)d_in[13], (const float*)d_in[14]};
    float* out = (float*)d_out;

    // per-batch workspace element counts (sized for max df=512)
    const long eKT = (long)HH * KVD * NSEQ;   // shorts (KT[g][h][j][n])
    const long eQ  = (long)HH * 512 * NSEQ;   // shorts (Q[g][h][e][n])
    const long eS  = (long)HH * 512 * KVD;    // floats (S[g][h][e][j])
    const long eCh = (long)HH * NSEQ * 512;   // shorts (Ch[g][h][n][e])
    const long perBatchBytes = (2 * eKT + eQ + eCh) * 2 + eS * 4
                             + (long)HH * (2 + 2 * 120) * 4;
    int G = 8;
    while (G > 1 && (long)G * perBatchBytes + 1024 > (long)ws_size) G >>= 1;

    char* p = (char*)d_ws;
    short* KTb = (short*)p; p += (long)G * eKT * 2;
    short* Vb  = (short*)p; p += (long)G * eKT * 2;
    short* Qb  = (short*)p; p += (long)G * eQ  * 2;
    float* Sb  = (float*)p; p += (long)G * eS  * 4;
    short* Chb = (short*)p; p += (long)G * eCh * 2;
    float* statsb   = (float*)p; p += (long)G * HH * 2 * 4;
    float* partialb = (float*)p;

    const float scale = 1.0f / sqrtf((float)KVD);
    const int dfs[4] = {64, 128, 256, 512};
    long outBase[4];
    {
        long acc = 0;
        for (int br = 0; br < 4; ++br) { outBase[br] = acc; acc += (long)BATCH * NSEQ * dfs[br]; }
    }

    const dim3 blk(256);
    for (int b0 = 0; b0 < BATCH; b0 += G) {
        const float* embA = emb_all + (long)b0 * NSEQ * KVD;

        // KT[g][h][j][n] = sum_k WK[h][j][k] emb_all[b0+g][n][k]  (M=KVD,Nc=N,K=KVD)
        mfma_nt<64, 128, float, float, short><<<dim3(NSEQ / 128, KVD / 64, G * HH), blk, 0, stream>>>(
            WK, embA, KTb, KVD, KVD, NSEQ, KVD, 1.0f, 1, 0, 0,
            (long)KVD * KVD, 0,
            0, (long)NSEQ * KVD,
            (long)KVD * NSEQ, (long)HH * KVD * NSEQ, 1);

        // V[g][h][n][j] = sum_k emb_all[b0+g][n][k] WV[h][j][k]  (M=N,Nc=KVD,K=KVD)
        mfma_nt<128, 64, float, float, short><<<dim3(KVD / 64, NSEQ / 128, G * HH), blk, 0, stream>>>(
            embA, WV, Vb, KVD, KVD, KVD, KVD, 1.0f, 1, 0, 0,
            0, (long)NSEQ * KVD,
            (long)KVD * KVD, 0,
            (long)NSEQ * KVD, (long)HH * NSEQ * KVD, 1);

        for (int br = 0; br < 4; ++br) {
            const int df = dfs[br];
            const int nchunks = df * KVD / SCHUNK;
            const float* embB = emb[br] + (long)b0 * NSEQ * df;

            // Q[g][h][e][n] = sum_d WQ[h][e][d] emb[b0+g][n][d]  (M=df,Nc=N,K=df)
            mfma_nt<64, 128, float, float, short><<<dim3(NSEQ / 128, df / 64, G * HH), blk, 0, stream>>>(
                WQ[br], embB, Qb, df, df, NSEQ, df, 1.0f, 1, 0, 0,
                (long)df * df, 0,
                0, (long)NSEQ * df,
                (long)df * NSEQ, (long)HH * df * NSEQ, 1);

            // S[g][h][e][j] = scale * sum_n Q[g][h][e][n] KT[g][h][j][n]  (M=df,Nc=KVD,K=N)
            if (df >= 128) {
                mfma_nt<128, 64, short, short, float><<<dim3(KVD / 64, df / 128, G * HH), blk, 0, stream>>>(
                    Qb, KTb, Sb, NSEQ, NSEQ, KVD, NSEQ, scale, 1, 0, 0,
                    (long)df * NSEQ, (long)HH * df * NSEQ,
                    (long)KVD * NSEQ, (long)HH * KVD * NSEQ,
                    (long)df * KVD, (long)HH * df * KVD, 1);
            } else {
                mfma_nt<64, 64, short, short, float><<<dim3(KVD / 64, df / 64, G * HH), blk, 0, stream>>>(
                    Qb, KTb, Sb, NSEQ, NSEQ, KVD, NSEQ, scale, 1, 0, 0,
                    (long)df * NSEQ, (long)HH * df * NSEQ,
                    (long)KVD * NSEQ, (long)HH * KVD * NSEQ,
                    (long)df * KVD, (long)HH * df * KVD, 1);
            }

            stats_partial_kernel<<<dim3(nchunks, G * HH), dim3(256), 0, stream>>>(Sb, partialb, df, nchunks);
            stats_final_kernel  <<<dim3(G * HH), dim3(128), 0, stream>>>(partialb, statsb, df, nchunks);
            softmax_kernel<<<dim3(df, G * HH), dim3(256), 0, stream>>>(Sb, statsb, df);

            // Ch[g][h][n][e] = sum_j V[g][h][n][j] A[g][h][e][j]  (M=N,Nc=df,K=KVD)
            mfma_nt<128, 64, short, float, short><<<dim3(df / 64, NSEQ / 128, G * HH), blk, 0, stream>>>(
                Vb, Sb, Chb, KVD, KVD, df, KVD, 1.0f, 1, 0, 0,
                (long)NSEQ * KVD, (long)HH * NSEQ * KVD,
                (long)df * KVD, (long)HH * df * KVD,
                (long)NSEQ * df, (long)HH * NSEQ * df, 1);

            // O[b0+g][n][f] = (1/H) sum_h sum_e Ch[g][h][n][e] WO[f][e]  (M=N,Nc=df,K=df)
            mfma_nt<128, 64, short, float, float><<<dim3(df / 64, NSEQ / 128, G), blk, 0, stream>>>(
                Chb, WO[br], out + outBase[br] + (long)b0 * NSEQ * df,
                df, df, df, df, 1.0f / HH, HH, (long)NSEQ * df, 0,
                0, (long)HH * NSEQ * df,
                0, 0,
                0, (long)NSEQ * df, 0);
        }
    }
}

// Round 6
// 1154.806 us; speedup vs baseline: 19.7474x; 1.0765x over previous
//
#include <hip/hip_runtime.h>
#include <hip/hip_bf16.h>
#include <math.h>

#define HH    4
#define NSEQ  1024
#define KVD   960    // true KV dim
#define KVP   1024   // padded KV dim (zero pad) so every tile dim is 128-divisible
#define BATCH 8
#define SCHUNK 4096  // floats per stats_partial block; df*KVP is always a multiple

static constexpr float EPS = 1e-5f;

typedef __attribute__((ext_vector_type(8))) short short8;   // 8 bf16
typedef __attribute__((ext_vector_type(4))) float f32x4;    // MFMA C/D frag

__device__ __forceinline__ short f2bf(float x) {
    union { __hip_bfloat16 h; short s; } u;
    u.h = __float2bfloat16(x);
    return u.s;
}
__device__ __forceinline__ short8 cvt8(const float* __restrict__ g) {
    const float4 a = *(const float4*)g;
    const float4 b = *(const float4*)(g + 4);
    short8 t;
    t[0] = f2bf(a.x); t[1] = f2bf(a.y); t[2] = f2bf(a.z); t[3] = f2bf(a.w);
    t[4] = f2bf(b.x); t[5] = f2bf(b.y); t[6] = f2bf(b.z); t[7] = f2bf(b.w);
    return t;
}

// ---- one-time input converts -------------------------------------------------
__global__ void conv_bf16_kernel(const float* __restrict__ src, short* __restrict__ dst, long n8)
{
    const long u = (long)blockIdx.x * 256 + threadIdx.x;
    if (u >= n8) return;
    *(short8*)(dst + u * 8) = cvt8(src + u * 8);
}

// WK/WV: [H][960][960] fp32 -> [H][1024][960] bf16, rows 960..1023 zeroed
__global__ void conv_padw_kernel(const float* __restrict__ src, short* __restrict__ dst)
{
    const long u = (long)blockIdx.x * 256 + threadIdx.x;  // one short8 per thread
    const int cpr = KVD / 8;                              // 120
    const int c8  = (int)(u % cpr) * 8;
    const int row = (int)((u / cpr) % KVP);
    const int h   = (int)(u / ((long)cpr * KVP));
    short8 t = (short8){0,0,0,0,0,0,0,0};
    if (row < KVD) t = cvt8(src + ((long)h * KVD + row) * KVD + c8);
    *(short8*)(dst + ((long)h * KVP + row) * KVD + c8) = t;
}

// ---- LDS staging: ROWS x 32 bf16, rows padded to 40 shorts (80 B) ------------
template<int ROWS>
__device__ __forceinline__ void stage_tile(short (*dst)[40], const short* __restrict__ src,
                                           int ld, int tid)
{
    #pragma unroll
    for (int p = 0; p < ROWS / 64; ++p) {
        const int row = p * 64 + (tid >> 2);
        const int c8  = (tid & 3) * 8;
        *(short8*)&dst[row][c8] = *(const short8*)(src + (long)row * ld + c8);
    }
}

// ---------------------------------------------------------------------------
// bf16-MFMA NT GEMM, 1D grid with XCD-clustered swizzle.
// C[M,Nc] = alpha * sum_ib A_ib[M,K] @ B_ib[Nc,K]^T   (K contiguous both sides)
// Block = 256 thr = 4 waves (2x2); wave tile (TM/2)x(TN/2) of 16x16x32 MFMAs.
// grid.x = gx*gy*Z; if Z%8==0, XCD (bid&7) owns Z/8 complete z-slices so the
// per-XCD L2 working set is one slice's strips (fits 4 MiB).
// ---------------------------------------------------------------------------
template<int TM, int TN, typename TC>
__global__ __launch_bounds__(256) void mfma_nt(
    const short* __restrict__ A, const short* __restrict__ B, TC* __restrict__ C,
    int lda, int ldb, int ldc, int K, float alpha, int inner, long sA, long sB,
    long zAh, long zAg, long zBh, long zBg, long zCh, long zCg,
    int splitH, int gx, int gy)
{
    constexpr int MT = TM / 32;
    constexpr int NT = TN / 32;
    __shared__ short As[TM][40];
    __shared__ short Bs[TN][40];

    const int bps = gx * gy;
    const int Z   = gridDim.x / bps;
    int z, r;
    if ((Z & 7) == 0) {
        const int xcd = blockIdx.x & 7;
        const int j   = blockIdx.x >> 3;
        const int spx = Z >> 3;             // slices per XCD
        z = xcd * spx + j / bps;
        r = j % bps;
    } else {
        z = blockIdx.x / bps;
        r = blockIdx.x % bps;
    }
    const int x = r % gx, y = r / gx;
    int h, g;
    if (splitH) { h = z & (HH - 1); g = z >> 2; }
    else        { h = 0;            g = z;      }
    A += (long)h * zAh + (long)g * zAg;
    B += (long)h * zBh + (long)g * zBg;
    C += (long)h * zCh + (long)g * zCg;

    const int tid  = threadIdx.x;
    const int lane = tid & 63;
    const int w    = tid >> 6;
    const int wr   = w >> 1;
    const int wc   = w & 1;
    const int quad = lane >> 4;
    const int l16  = lane & 15;
    const long m0  = (long)y * TM;
    const long n0  = (long)x * TN;

    f32x4 acc[MT][NT];
    #pragma unroll
    for (int i = 0; i < MT; ++i)
        #pragma unroll
        for (int j2 = 0; j2 < NT; ++j2)
            acc[i][j2] = (f32x4){0.f, 0.f, 0.f, 0.f};

    for (int ib = 0; ib < inner; ++ib) {
        const short* Ab = A + (long)ib * sA + m0 * lda;
        const short* Bb = B + (long)ib * sB + n0 * ldb;
        for (int k0 = 0; k0 < K; k0 += 32) {
            stage_tile<TM>(As, Ab + k0, lda, tid);
            stage_tile<TN>(Bs, Bb + k0, ldb, tid);
            __syncthreads();
            short8 af[MT], bfr[NT];
            #pragma unroll
            for (int i = 0; i < MT; ++i)
                af[i] = *(const short8*)&As[wr * (TM / 2) + i * 16 + l16][quad * 8];
            #pragma unroll
            for (int j2 = 0; j2 < NT; ++j2)
                bfr[j2] = *(const short8*)&Bs[wc * (TN / 2) + j2 * 16 + l16][quad * 8];
            #pragma unroll
            for (int i = 0; i < MT; ++i)
                #pragma unroll
                for (int j2 = 0; j2 < NT; ++j2)
                    acc[i][j2] = __builtin_amdgcn_mfma_f32_16x16x32_bf16(
                        af[i], bfr[j2], acc[i][j2], 0, 0, 0);
            __syncthreads();
        }
    }

    // C/D layout: col = lane&15, row = (lane>>4)*4 + reg   [m89-verified]
    #pragma unroll
    for (int i = 0; i < MT; ++i) {
        #pragma unroll
        for (int j2 = 0; j2 < NT; ++j2) {
            const long row = m0 + wr * (TM / 2) + i * 16 + quad * 4;
            const long col = n0 + wc * (TN / 2) + j2 * 16 + l16;
            #pragma unroll
            for (int rr = 0; rr < 4; ++rr) {
                const float v = alpha * acc[i][j2][rr];
                if constexpr (sizeof(TC) == 4)
                    C[(row + rr) * ldc + col] = v;
                else
                    C[(row + rr) * ldc + col] = f2bf(v);
            }
        }
    }
}

// ---- instance-norm stats, phase 1: grid (df/4, G*H), block 256 ---------------
// S rows are ld=KVP with zero pad cols (zeros don't perturb sums).
__global__ void stats_partial_kernel(const float* __restrict__ S,
                                     float* __restrict__ partial,
                                     int df, int nchunks)
{
    const int y = blockIdx.y;
    const int c = blockIdx.x;
    const float* p = S + (long)y * df * KVP + (long)c * SCHUNK;
    float s = 0.f, ss = 0.f;
    #pragma unroll
    for (int k = 0; k < 4; ++k) {
        const float4 v = *(const float4*)(p + 4 * (threadIdx.x + 256 * k));
        s  += v.x + v.y + v.z + v.w;
        ss += v.x * v.x + v.y * v.y + v.z * v.z + v.w * v.w;
    }
    __shared__ float rs[256], rss[256];
    rs[threadIdx.x] = s; rss[threadIdx.x] = ss;
    __syncthreads();
    for (int o = 128; o > 0; o >>= 1) {
        if (threadIdx.x < o) {
            rs[threadIdx.x]  += rs[threadIdx.x + o];
            rss[threadIdx.x] += rss[threadIdx.x + o];
        }
        __syncthreads();
    }
    if (threadIdx.x == 0) {
        partial[((long)y * nchunks + c) * 2]     = rs[0];
        partial[((long)y * nchunks + c) * 2 + 1] = rss[0];
    }
}

// ---- stats phase 2: grid (G*H), block 128. Divisor is the REAL count df*960.
__global__ void stats_final_kernel(const float* __restrict__ partial,
                                   float* __restrict__ stats,
                                   int df, int nchunks)
{
    const int y = blockIdx.x;
    const int t = threadIdx.x;
    float s = 0.f, ss = 0.f;
    for (int c = t; c < nchunks; c += 128) {
        s  += partial[((long)y * nchunks + c) * 2];
        ss += partial[((long)y * nchunks + c) * 2 + 1];
    }
    __shared__ float rs[128], rss[128];
    rs[t] = s; rss[t] = ss;
    __syncthreads();
    for (int o = 64; o > 0; o >>= 1) {
        if (t < o) { rs[t] += rs[t + o]; rss[t] += rss[t + o]; }
        __syncthreads();
    }
    if (t == 0) {
        const float n = (float)(df * KVD);
        const float mean = rs[0] / n;
        const float var  = rss[0] / n - mean * mean;
        stats[2 * y]     = mean;
        stats[2 * y + 1] = rsqrtf(var + EPS);
    }
}

// ---- softmax over real 960 cols; writes bf16 A-operand with pad cols zeroed.
// grid (df, G*H), block 256
__global__ void softmax_kernel(const float* __restrict__ S,
                               short* __restrict__ Sa,
                               const float* __restrict__ stats, int df)
{
    const int y = blockIdx.y;
    const float mean = stats[2 * y];
    const float rstd = stats[2 * y + 1];
    const float* row = S  + ((long)y * df + blockIdx.x) * KVP;
    short*       orow = Sa + ((long)y * df + blockIdx.x) * KVP;
    const int t = threadIdx.x;

    float x[4];
    float mx = -1e30f;
    #pragma unroll
    for (int i = 0; i < 4; ++i) {
        const int j = t + i * 256;
        x[i] = (j < KVD) ? (row[j] - mean) * rstd : -1e30f;
        mx = fmaxf(mx, x[i]);
    }
    __shared__ float red[256];
    red[t] = mx; __syncthreads();
    for (int o = 128; o > 0; o >>= 1) {
        if (t < o) red[t] = fmaxf(red[t], red[t + o]);
        __syncthreads();
    }
    mx = red[0];
    __syncthreads();

    float e[4];
    float sum = 0.f;
    #pragma unroll
    for (int i = 0; i < 4; ++i) {
        const int j = t + i * 256;
        e[i] = (j < KVD) ? __expf(x[i] - mx) : 0.f;
        sum += e[i];
    }
    red[t] = sum; __syncthreads();
    for (int o = 128; o > 0; o >>= 1) {
        if (t < o) red[t] += red[t + o];
        __syncthreads();
    }
    const float inv = 1.0f / red[0];
    #pragma unroll
    for (int i = 0; i < 4; ++i) {
        const int j = t + i * 256;
        if (j < KVP) orow[j] = (j < KVD) ? f2bf(e[i] * inv) : (short)0;
    }
}

// ---------------------------------------------------------------------------
extern "C" void kernel_launch(void* const* d_in, const int* in_sizes, int n_in,
                              void* d_out, int out_size, void* d_ws, size_t ws_size,
                              hipStream_t stream)
{
    const float* emb[4]  = {(const float*)d_in[0], (const float*)d_in[1],
                            (const float*)d_in[2], (const float*)d_in[3]};
    const float* emb_all = (const float*)d_in[4];
    const float* WQ[4]   = {(const float*)d_in[5], (const float*)d_in[6],
                            (const float*)d_in[7], (const float*)d_in[8]};
    const float* WK      = (const float*)d_in[9];
    const float* WV      = (const float*)d_in[10];
    const float* WO[4]   = {(const float*)d_in[11], (const float*)d_in[12],
                            (const float*)d_in[13], (const float*)d_in[14]};
    float* out = (float*)d_out;

    const int dfs[4] = {64, 128, 256, 512};
    const long N = NSEQ;

    // ---- workspace budget: pre-converted inputs (global) + per-g buffers
    const long eAll  = (long)BATCH * N * KVD;         // emb_all bf16
    const long eWKp  = (long)HH * KVP * KVD;          // padded weight bf16
    long preBytes = eAll * 2 + 2 * eWKp * 2;
    for (int br = 0; br < 4; ++br)
        preBytes += ((long)BATCH * N * dfs[br] + (long)HH * dfs[br] * dfs[br]
                    + (long)dfs[br] * dfs[br]) * 2;
    const long perG = ((long)HH * KVP * N) * 2        // KT
                    + ((long)HH * N * KVP) * 2        // V
                    + ((long)HH * 512 * N) * 2        // Q
                    + ((long)HH * 512 * KVP) * 4      // S (fp32)
                    + ((long)HH * 512 * KVP) * 2      // Sa (bf16)
                    + ((long)HH * N * 512) * 2        // Ch
                    + (long)HH * (2 + 256) * 4;       // stats + partial
    int G = 8;
    while (G > 1 && preBytes + (long)G * perG + 4096 > (long)ws_size) G >>= 1;

    // ---- carve workspace
    char* p = (char*)d_ws;
    short* embAllp = (short*)p; p += eAll * 2;
    short* embp[4]; short* WQp[4]; short* WOp[4];
    for (int br = 0; br < 4; ++br) { embp[br] = (short*)p; p += (long)BATCH * N * dfs[br] * 2; }
    for (int br = 0; br < 4; ++br) { WQp[br]  = (short*)p; p += (long)HH * dfs[br] * dfs[br] * 2; }
    short* WKp = (short*)p; p += eWKp * 2;
    short* WVp = (short*)p; p += eWKp * 2;
    for (int br = 0; br < 4; ++br) { WOp[br]  = (short*)p; p += (long)dfs[br] * dfs[br] * 2; }
    short* KTb = (short*)p; p += (long)G * HH * KVP * N * 2;
    short* Vb  = (short*)p; p += (long)G * HH * N * KVP * 2;
    short* Qb  = (short*)p; p += (long)G * HH * 512 * N * 2;
    float* Sb  = (float*)p; p += (long)G * HH * 512 * KVP * 4;
    short* Sab = (short*)p; p += (long)G * HH * 512 * KVP * 2;
    short* Chb = (short*)p; p += (long)G * HH * N * 512 * 2;
    float* statsb   = (float*)p; p += (long)G * HH * 2 * 4;
    float* partialb = (float*)p;

    // ---- one-time converts (re-run every call; ws is re-poisoned each time)
    {
        long n8 = eAll / 8;
        conv_bf16_kernel<<<dim3((n8 + 255) / 256), dim3(256), 0, stream>>>(emb_all, embAllp, n8);
        for (int br = 0; br < 4; ++br) {
            n8 = (long)BATCH * N * dfs[br] / 8;
            conv_bf16_kernel<<<dim3((n8 + 255) / 256), dim3(256), 0, stream>>>(emb[br], embp[br], n8);
            n8 = (long)HH * dfs[br] * dfs[br] / 8;
            conv_bf16_kernel<<<dim3((n8 + 255) / 256), dim3(256), 0, stream>>>(WQ[br], WQp[br], n8);
            n8 = (long)dfs[br] * dfs[br] / 8;
            conv_bf16_kernel<<<dim3((n8 + 255) / 256), dim3(256), 0, stream>>>(WO[br], WOp[br], n8);
        }
        const int padw_blocks = HH * KVP * (KVD / 8) / 256;   // 1920
        conv_padw_kernel<<<dim3(padw_blocks), dim3(256), 0, stream>>>(WK, WKp);
        conv_padw_kernel<<<dim3(padw_blocks), dim3(256), 0, stream>>>(WV, WVp);
    }

    const float scale = 1.0f / sqrtf((float)KVD);
    long outBase[4];
    {
        long acc = 0;
        for (int br = 0; br < 4; ++br) { outBase[br] = acc; acc += (long)BATCH * N * dfs[br]; }
    }

    const dim3 blk(256);
    for (int b0 = 0; b0 < BATCH; b0 += G) {
        const int Z = G * HH;
        const short* embA = embAllp + (long)b0 * N * KVD;

        // KT[g][h][j(1024)][n] = sum_k WKp[h][j][k] embA[g][n][k]   M=KVP,Nc=N,K=KVD
        mfma_nt<128, 128, short><<<dim3(8 * 8 * Z), blk, 0, stream>>>(
            WKp, embA, KTb, KVD, KVD, N, KVD, 1.0f, 1, 0, 0,
            (long)KVP * KVD, 0,
            0, (long)N * KVD,
            (long)KVP * N, (long)HH * KVP * N, 1, 8, 8);

        // V[g][h][n][j(1024)] = sum_k embA[g][n][k] WVp[h][j][k]    M=N,Nc=KVP,K=KVD
        mfma_nt<128, 128, short><<<dim3(8 * 8 * Z), blk, 0, stream>>>(
            embA, WVp, Vb, KVD, KVD, KVP, KVD, 1.0f, 1, 0, 0,
            0, (long)N * KVD,
            (long)KVP * KVD, 0,
            (long)N * KVP, (long)HH * N * KVP, 1, 8, 8);

        for (int br = 0; br < 4; ++br) {
            const int df = dfs[br];
            const int nchunks = df * KVP / SCHUNK;   // df/4
            const short* embB = embp[br] + (long)b0 * N * df;

            // Q[g][h][e][n] = sum_d WQp[h][e][d] embB[g][n][d]      M=df,Nc=N,K=df
            if (df >= 128)
                mfma_nt<128, 128, short><<<dim3(8 * (df / 128) * Z), blk, 0, stream>>>(
                    WQp[br], embB, Qb, df, df, N, df, 1.0f, 1, 0, 0,
                    (long)df * df, 0, 0, (long)N * df,
                    (long)df * N, (long)HH * df * N, 1, 8, df / 128);
            else
                mfma_nt<64, 128, short><<<dim3(8 * 1 * Z), blk, 0, stream>>>(
                    WQp[br], embB, Qb, df, df, N, df, 1.0f, 1, 0, 0,
                    (long)df * df, 0, 0, (long)N * df,
                    (long)df * N, (long)HH * df * N, 1, 8, 1);

            // S[g][h][e][j(1024)] = scale * sum_n Q[e][n] KT[j][n]  M=df,Nc=KVP,K=N
            if (df >= 128)
                mfma_nt<128, 128, float><<<dim3(8 * (df / 128) * Z), blk, 0, stream>>>(
                    Qb, KTb, Sb, N, N, KVP, N, scale, 1, 0, 0,
                    (long)df * N, (long)HH * df * N,
                    (long)KVP * N, (long)HH * KVP * N,
                    (long)df * KVP, (long)HH * df * KVP, 1, 8, df / 128);
            else
                mfma_nt<64, 128, float><<<dim3(8 * 1 * Z), blk, 0, stream>>>(
                    Qb, KTb, Sb, N, N, KVP, N, scale, 1, 0, 0,
                    (long)df * N, (long)HH * df * N,
                    (long)KVP * N, (long)HH * KVP * N,
                    (long)df * KVP, (long)HH * df * KVP, 1, 8, 1);

            stats_partial_kernel<<<dim3(nchunks, Z), dim3(256), 0, stream>>>(Sb, partialb, df, nchunks);
            stats_final_kernel  <<<dim3(Z), dim3(128), 0, stream>>>(partialb, statsb, df, nchunks);
            softmax_kernel<<<dim3(df, Z), dim3(256), 0, stream>>>(Sb, Sab, statsb, df);

            // Ch[g][h][n][e] = sum_j V[n][j] Sa[e][j]               M=N,Nc=df,K=KVP
            if (df >= 128)
                mfma_nt<128, 128, short><<<dim3((df / 128) * 8 * Z), blk, 0, stream>>>(
                    Vb, Sab, Chb, KVP, KVP, df, KVP, 1.0f, 1, 0, 0,
                    (long)N * KVP, (long)HH * N * KVP,
                    (long)df * KVP, (long)HH * df * KVP,
                    (long)N * df, (long)HH * N * df, 1, df / 128, 8);
            else
                mfma_nt<128, 64, short><<<dim3(1 * 8 * Z), blk, 0, stream>>>(
                    Vb, Sab, Chb, KVP, KVP, df, KVP, 1.0f, 1, 0, 0,
                    (long)N * KVP, (long)HH * N * KVP,
                    (long)df * KVP, (long)HH * df * KVP,
                    (long)N * df, (long)HH * N * df, 1, 1, 8);

            // O[b0+g][n][f] = (1/H) sum_h sum_e Ch[g][h][n][e] WOp[f][e]  M=N,Nc=df,K=df
            if (df >= 128)
                mfma_nt<128, 128, float><<<dim3((df / 128) * 8 * G), blk, 0, stream>>>(
                    Chb, WOp[br], out + outBase[br] + (long)b0 * N * df,
                    df, df, df, df, 1.0f / HH, HH, (long)N * df, 0,
                    0, (long)HH * N * df, 0, 0,
                    0, (long)N * df, 0, df / 128, 8);
            else
                mfma_nt<128, 64, float><<<dim3(1 * 8 * G), blk, 0, stream>>>(
                    Chb, WOp[br], out + outBase[br] + (long)b0 * N * df,
                    df, df, df, df, 1.0f / HH, HH, (long)N * df, 0,
                    0, (long)HH * N * df, 0, 0,
                    0, (long)N * df, 0, 1, 8);
        }
    }
}

// Round 7
// 1110.722 us; speedup vs baseline: 20.5312x; 1.0397x over previous
//
#include <hip/hip_runtime.h>
#include <hip/hip_bf16.h>
#include <math.h>

#define HH    4
#define NSEQ  1024
#define KVD   960    // true KV dim
#define KVP   1024   // padded KV dim (zero pad) so every tile dim is 128-divisible
#define BATCH 8
#define SCHUNK 4096  // floats per stats_partial block; df*KVP is always a multiple

static constexpr float EPS = 1e-5f;

typedef __attribute__((ext_vector_type(8))) short short8;   // 8 bf16
typedef __attribute__((ext_vector_type(4))) float f32x4;    // MFMA C/D frag

__device__ __forceinline__ short f2bf(float x) {
    union { __hip_bfloat16 h; short s; } u;
    u.h = __float2bfloat16(x);
    return u.s;
}
__device__ __forceinline__ short8 cvt8(const float* __restrict__ g) {
    const float4 a = *(const float4*)g;
    const float4 b = *(const float4*)(g + 4);
    short8 t;
    t[0] = f2bf(a.x); t[1] = f2bf(a.y); t[2] = f2bf(a.z); t[3] = f2bf(a.w);
    t[4] = f2bf(b.x); t[5] = f2bf(b.y); t[6] = f2bf(b.z); t[7] = f2bf(b.w);
    return t;
}

// ---- one-time input converts -------------------------------------------------
__global__ void conv_bf16_kernel(const float* __restrict__ src, short* __restrict__ dst, long n8)
{
    const long u = (long)blockIdx.x * 256 + threadIdx.x;
    if (u >= n8) return;
    *(short8*)(dst + u * 8) = cvt8(src + u * 8);
}

// WK/WV: [H][960][960] fp32 -> [H][1024][960] bf16, rows 960..1023 zeroed
__global__ void conv_padw_kernel(const float* __restrict__ src, short* __restrict__ dst)
{
    const long u = (long)blockIdx.x * 256 + threadIdx.x;  // one short8 per thread
    const int cpr = KVD / 8;                              // 120
    const int c8  = (int)(u % cpr) * 8;
    const int row = (int)((u / cpr) % KVP);
    const int h   = (int)(u / ((long)cpr * KVP));
    short8 t = (short8){0,0,0,0,0,0,0,0};
    if (row < KVD) t = cvt8(src + ((long)h * KVD + row) * KVD + c8);
    *(short8*)(dst + ((long)h * KVP + row) * KVD + c8) = t;
}

// ---- async LDS staging: ROWS x 32 bf16, UNPADDED 64B rows, chunk-XOR swizzle.
// LDS physical chunk (row, c16p) holds logical 16B-chunk ((c16p - row) & 3).
// Each wave DMAs 1KB (16 rows) per issue: dst base is wave-uniform, HW scatters
// lane i -> base + i*16  [m104/m108].
template<int ROWS>
__device__ __forceinline__ void stage_async(short (*dst)[32], const short* __restrict__ src,
                                            int ld, int w, int lane)
{
    #pragma unroll
    for (int p = 0; p < ROWS / 64; ++p) {
        const int rbase = p * 64 + w * 16;
        const int row   = rbase + (lane >> 2);
        const int c16l  = ((lane & 3) - row) & 3;   // logical chunk landing at this slot
        const short* g  = src + (long)row * ld + c16l * 8;
        __builtin_amdgcn_global_load_lds(
            (const __attribute__((address_space(1))) void*)g,
            (__attribute__((address_space(3))) void*)&dst[rbase][0],
            16, 0, 0);
    }
}

// ---------------------------------------------------------------------------
// bf16-MFMA NT GEMM, 1D grid with XCD-clustered swizzle, async LDS staging.
// C[M,Nc] = alpha * sum_ib A_ib[M,K] @ B_ib[Nc,K]^T   (K contiguous both sides)
// Block = 256 thr = 4 waves (2x2); wave tile (TM/2)x(TN/2) of 16x16x32 MFMAs.
// grid.x = gx*gy*Z; if Z%8==0, XCD (bid&7) owns Z/8 complete z-slices so the
// per-XCD L2 working set is one slice's strips (fits 4 MiB).
// ---------------------------------------------------------------------------
template<int TM, int TN, typename TC>
__global__ __launch_bounds__(256) void mfma_nt(
    const short* __restrict__ A, const short* __restrict__ B, TC* __restrict__ C,
    int lda, int ldb, int ldc, int K, float alpha, int inner, long sA, long sB,
    long zAh, long zAg, long zBh, long zBg, long zCh, long zCg,
    int splitH, int gx, int gy)
{
    constexpr int MT = TM / 32;
    constexpr int NT = TN / 32;
    __shared__ short As[TM][32];
    __shared__ short Bs[TN][32];

    const int bps = gx * gy;
    const int Z   = gridDim.x / bps;
    int z, r;
    if ((Z & 7) == 0) {
        const int xcd = blockIdx.x & 7;
        const int j   = blockIdx.x >> 3;
        const int spx = Z >> 3;             // slices per XCD
        z = xcd * spx + j / bps;
        r = j % bps;
    } else {
        z = blockIdx.x / bps;
        r = blockIdx.x % bps;
    }
    const int x = r % gx, y = r / gx;
    int h, g;
    if (splitH) { h = z & (HH - 1); g = z >> 2; }
    else        { h = 0;            g = z;      }
    A += (long)h * zAh + (long)g * zAg;
    B += (long)h * zBh + (long)g * zBg;
    C += (long)h * zCh + (long)g * zCg;

    const int tid  = threadIdx.x;
    const int lane = tid & 63;
    const int w    = tid >> 6;
    const int wr   = w >> 1;
    const int wc   = w & 1;
    const int quad = lane >> 4;
    const int l16  = lane & 15;
    const long m0  = (long)y * TM;
    const long n0  = (long)x * TN;

    f32x4 acc[MT][NT];
    #pragma unroll
    for (int i = 0; i < MT; ++i)
        #pragma unroll
        for (int j2 = 0; j2 < NT; ++j2)
            acc[i][j2] = (f32x4){0.f, 0.f, 0.f, 0.f};

    for (int ib = 0; ib < inner; ++ib) {
        const short* Ab = A + (long)ib * sA + m0 * lda;
        const short* Bb = B + (long)ib * sB + n0 * ldb;
        for (int k0 = 0; k0 < K; k0 += 32) {
            stage_async<TM>(As, Ab + k0, lda, w, lane);
            stage_async<TN>(Bs, Bb + k0, ldb, w, lane);
            __syncthreads();   // drains vmcnt -> DMA'd LDS data visible
            short8 af[MT], bfr[NT];
            #pragma unroll
            for (int i = 0; i < MT; ++i) {
                const int rowA = wr * (TM / 2) + i * 16 + l16;
                af[i] = *(const short8*)&As[rowA][((quad + rowA) & 3) * 8];
            }
            #pragma unroll
            for (int j2 = 0; j2 < NT; ++j2) {
                const int rowB = wc * (TN / 2) + j2 * 16 + l16;
                bfr[j2] = *(const short8*)&Bs[rowB][((quad + rowB) & 3) * 8];
            }
            #pragma unroll
            for (int i = 0; i < MT; ++i)
                #pragma unroll
                for (int j2 = 0; j2 < NT; ++j2)
                    acc[i][j2] = __builtin_amdgcn_mfma_f32_16x16x32_bf16(
                        af[i], bfr[j2], acc[i][j2], 0, 0, 0);
            __syncthreads();
        }
    }

    // C/D layout: col = lane&15, row = (lane>>4)*4 + reg   [m89-verified]
    #pragma unroll
    for (int i = 0; i < MT; ++i) {
        #pragma unroll
        for (int j2 = 0; j2 < NT; ++j2) {
            const long row = m0 + wr * (TM / 2) + i * 16 + quad * 4;
            const long col = n0 + wc * (TN / 2) + j2 * 16 + l16;
            #pragma unroll
            for (int rr = 0; rr < 4; ++rr) {
                const float v = alpha * acc[i][j2][rr];
                if constexpr (sizeof(TC) == 4)
                    C[(row + rr) * ldc + col] = v;
                else
                    C[(row + rr) * ldc + col] = f2bf(v);
            }
        }
    }
}

// ---- instance-norm stats, phase 1: grid (df/4, G*H), block 256 ---------------
// S rows are ld=KVP with zero pad cols (zeros don't perturb sums).
__global__ void stats_partial_kernel(const float* __restrict__ S,
                                     float* __restrict__ partial,
                                     int df, int nchunks)
{
    const int y = blockIdx.y;
    const int c = blockIdx.x;
    const float* p = S + (long)y * df * KVP + (long)c * SCHUNK;
    float s = 0.f, ss = 0.f;
    #pragma unroll
    for (int k = 0; k < 4; ++k) {
        const float4 v = *(const float4*)(p + 4 * (threadIdx.x + 256 * k));
        s  += v.x + v.y + v.z + v.w;
        ss += v.x * v.x + v.y * v.y + v.z * v.z + v.w * v.w;
    }
    __shared__ float rs[256], rss[256];
    rs[threadIdx.x] = s; rss[threadIdx.x] = ss;
    __syncthreads();
    for (int o = 128; o > 0; o >>= 1) {
        if (threadIdx.x < o) {
            rs[threadIdx.x]  += rs[threadIdx.x + o];
            rss[threadIdx.x] += rss[threadIdx.x + o];
        }
        __syncthreads();
    }
    if (threadIdx.x == 0) {
        partial[((long)y * nchunks + c) * 2]     = rs[0];
        partial[((long)y * nchunks + c) * 2 + 1] = rss[0];
    }
}

// ---- stats phase 2: grid (G*H), block 128. Divisor is the REAL count df*960.
__global__ void stats_final_kernel(const float* __restrict__ partial,
                                   float* __restrict__ stats,
                                   int df, int nchunks)
{
    const int y = blockIdx.x;
    const int t = threadIdx.x;
    float s = 0.f, ss = 0.f;
    for (int c = t; c < nchunks; c += 128) {
        s  += partial[((long)y * nchunks + c) * 2];
        ss += partial[((long)y * nchunks + c) * 2 + 1];
    }
    __shared__ float rs[128], rss[128];
    rs[t] = s; rss[t] = ss;
    __syncthreads();
    for (int o = 64; o > 0; o >>= 1) {
        if (t < o) { rs[t] += rs[t + o]; rss[t] += rss[t + o]; }
        __syncthreads();
    }
    if (t == 0) {
        const float n = (float)(df * KVD);
        const float mean = rs[0] / n;
        const float var  = rss[0] / n - mean * mean;
        stats[2 * y]     = mean;
        stats[2 * y + 1] = rsqrtf(var + EPS);
    }
}

// ---- softmax over real 960 cols; writes bf16 A-operand with pad cols zeroed.
// grid (df, G*H), block 256
__global__ void softmax_kernel(const float* __restrict__ S,
                               short* __restrict__ Sa,
                               const float* __restrict__ stats, int df)
{
    const int y = blockIdx.y;
    const float mean = stats[2 * y];
    const float rstd = stats[2 * y + 1];
    const float* row = S  + ((long)y * df + blockIdx.x) * KVP;
    short*       orow = Sa + ((long)y * df + blockIdx.x) * KVP;
    const int t = threadIdx.x;

    float x[4];
    float mx = -1e30f;
    #pragma unroll
    for (int i = 0; i < 4; ++i) {
        const int j = t + i * 256;
        x[i] = (j < KVD) ? (row[j] - mean) * rstd : -1e30f;
        mx = fmaxf(mx, x[i]);
    }
    __shared__ float red[256];
    red[t] = mx; __syncthreads();
    for (int o = 128; o > 0; o >>= 1) {
        if (t < o) red[t] = fmaxf(red[t], red[t + o]);
        __syncthreads();
    }
    mx = red[0];
    __syncthreads();

    float e[4];
    float sum = 0.f;
    #pragma unroll
    for (int i = 0; i < 4; ++i) {
        const int j = t + i * 256;
        e[i] = (j < KVD) ? __expf(x[i] - mx) : 0.f;
        sum += e[i];
    }
    red[t] = sum; __syncthreads();
    for (int o = 128; o > 0; o >>= 1) {
        if (t < o) red[t] += red[t + o];
        __syncthreads();
    }
    const float inv = 1.0f / red[0];
    #pragma unroll
    for (int i = 0; i < 4; ++i) {
        const int j = t + i * 256;
        if (j < KVP) orow[j] = (j < KVD) ? f2bf(e[i] * inv) : (short)0;
    }
}

// ---------------------------------------------------------------------------
extern "C" void kernel_launch(void* const* d_in, const int* in_sizes, int n_in,
                              void* d_out, int out_size, void* d_ws, size_t ws_size,
                              hipStream_t stream)
{
    const float* emb[4]  = {(const float*)d_in[0], (const float*)d_in[1],
                            (const float*)d_in[2], (const float*)d_in[3]};
    const float* emb_all = (const float*)d_in[4];
    const float* WQ[4]   = {(const float*)d_in[5], (const float*)d_in[6],
                            (const float*)d_in[7], (const float*)d_in[8]};
    const float* WK      = (const float*)d_in[9];
    const float* WV      = (const float*)d_in[10];
    const float* WO[4]   = {(const float*)d_in[11], (const float*)d_in[12],
                            (const float*)d_in[13], (const float*)d_in[14]};
    float* out = (float*)d_out;

    const int dfs[4] = {64, 128, 256, 512};
    const long N = NSEQ;

    // ---- workspace budget: pre-converted inputs (global) + per-g buffers
    const long eAll  = (long)BATCH * N * KVD;         // emb_all bf16
    const long eWKp  = (long)HH * KVP * KVD;          // padded weight bf16
    long preBytes = eAll * 2 + 2 * eWKp * 2;
    for (int br = 0; br < 4; ++br)
        preBytes += ((long)BATCH * N * dfs[br] + (long)HH * dfs[br] * dfs[br]
                    + (long)dfs[br] * dfs[br]) * 2;
    const long perG = ((long)HH * KVP * N) * 2        // KT
                    + ((long)HH * N * KVP) * 2        // V
                    + ((long)HH * 512 * N) * 2        // Q
                    + ((long)HH * 512 * KVP) * 4      // S (fp32)
                    + ((long)HH * 512 * KVP) * 2      // Sa (bf16)
                    + ((long)HH * N * 512) * 2        // Ch
                    + (long)HH * (2 + 256) * 4;       // stats + partial
    int G = 8;
    while (G > 1 && preBytes + (long)G * perG + 4096 > (long)ws_size) G >>= 1;

    // ---- carve workspace
    char* p = (char*)d_ws;
    short* embAllp = (short*)p; p += eAll * 2;
    short* embp[4]; short* WQp[4]; short* WOp[4];
    for (int br = 0; br < 4; ++br) { embp[br] = (short*)p; p += (long)BATCH * N * dfs[br] * 2; }
    for (int br = 0; br < 4; ++br) { WQp[br]  = (short*)p; p += (long)HH * dfs[br] * dfs[br] * 2; }
    short* WKp = (short*)p; p += eWKp * 2;
    short* WVp = (short*)p; p += eWKp * 2;
    for (int br = 0; br < 4; ++br) { WOp[br]  = (short*)p; p += (long)dfs[br] * dfs[br] * 2; }
    short* KTb = (short*)p; p += (long)G * HH * KVP * N * 2;
    short* Vb  = (short*)p; p += (long)G * HH * N * KVP * 2;
    short* Qb  = (short*)p; p += (long)G * HH * 512 * N * 2;
    float* Sb  = (float*)p; p += (long)G * HH * 512 * KVP * 4;
    short* Sab = (short*)p; p += (long)G * HH * 512 * KVP * 2;
    short* Chb = (short*)p; p += (long)G * HH * N * 512 * 2;
    float* statsb   = (float*)p; p += (long)G * HH * 2 * 4;
    float* partialb = (float*)p;

    // ---- one-time converts (re-run every call; ws is re-poisoned each time)
    {
        long n8 = eAll / 8;
        conv_bf16_kernel<<<dim3((n8 + 255) / 256), dim3(256), 0, stream>>>(emb_all, embAllp, n8);
        for (int br = 0; br < 4; ++br) {
            n8 = (long)BATCH * N * dfs[br] / 8;
            conv_bf16_kernel<<<dim3((n8 + 255) / 256), dim3(256), 0, stream>>>(emb[br], embp[br], n8);
            n8 = (long)HH * dfs[br] * dfs[br] / 8;
            conv_bf16_kernel<<<dim3((n8 + 255) / 256), dim3(256), 0, stream>>>(WQ[br], WQp[br], n8);
            n8 = (long)dfs[br] * dfs[br] / 8;
            conv_bf16_kernel<<<dim3((n8 + 255) / 256), dim3(256), 0, stream>>>(WO[br], WOp[br], n8);
        }
        const int padw_blocks = HH * KVP * (KVD / 8) / 256;   // 1920
        conv_padw_kernel<<<dim3(padw_blocks), dim3(256), 0, stream>>>(WK, WKp);
        conv_padw_kernel<<<dim3(padw_blocks), dim3(256), 0, stream>>>(WV, WVp);
    }

    const float scale = 1.0f / sqrtf((float)KVD);
    long outBase[4];
    {
        long acc = 0;
        for (int br = 0; br < 4; ++br) { outBase[br] = acc; acc += (long)BATCH * N * dfs[br]; }
    }

    const dim3 blk(256);
    for (int b0 = 0; b0 < BATCH; b0 += G) {
        const int Z = G * HH;
        const short* embA = embAllp + (long)b0 * N * KVD;

        // KT[g][h][j(1024)][n] = sum_k WKp[h][j][k] embA[g][n][k]   M=KVP,Nc=N,K=KVD
        mfma_nt<128, 128, short><<<dim3(8 * 8 * Z), blk, 0, stream>>>(
            WKp, embA, KTb, KVD, KVD, N, KVD, 1.0f, 1, 0, 0,
            (long)KVP * KVD, 0,
            0, (long)N * KVD,
            (long)KVP * N, (long)HH * KVP * N, 1, 8, 8);

        // V[g][h][n][j(1024)] = sum_k embA[g][n][k] WVp[h][j][k]    M=N,Nc=KVP,K=KVD
        mfma_nt<128, 128, short><<<dim3(8 * 8 * Z), blk, 0, stream>>>(
            embA, WVp, Vb, KVD, KVD, KVP, KVD, 1.0f, 1, 0, 0,
            0, (long)N * KVD,
            (long)KVP * KVD, 0,
            (long)N * KVP, (long)HH * N * KVP, 1, 8, 8);

        for (int br = 0; br < 4; ++br) {
            const int df = dfs[br];
            const int nchunks = df * KVP / SCHUNK;   // df/4
            const short* embB = embp[br] + (long)b0 * N * df;

            // Q[g][h][e][n] = sum_d WQp[h][e][d] embB[g][n][d]      M=df,Nc=N,K=df
            if (df >= 128)
                mfma_nt<128, 128, short><<<dim3(8 * (df / 128) * Z), blk, 0, stream>>>(
                    WQp[br], embB, Qb, df, df, N, df, 1.0f, 1, 0, 0,
                    (long)df * df, 0, 0, (long)N * df,
                    (long)df * N, (long)HH * df * N, 1, 8, df / 128);
            else
                mfma_nt<64, 128, short><<<dim3(8 * 1 * Z), blk, 0, stream>>>(
                    WQp[br], embB, Qb, df, df, N, df, 1.0f, 1, 0, 0,
                    (long)df * df, 0, 0, (long)N * df,
                    (long)df * N, (long)HH * df * N, 1, 8, 1);

            // S[g][h][e][j(1024)] = scale * sum_n Q[e][n] KT[j][n]  M=df,Nc=KVP,K=N
            if (df >= 128)
                mfma_nt<128, 128, float><<<dim3(8 * (df / 128) * Z), blk, 0, stream>>>(
                    Qb, KTb, Sb, N, N, KVP, N, scale, 1, 0, 0,
                    (long)df * N, (long)HH * df * N,
                    (long)KVP * N, (long)HH * KVP * N,
                    (long)df * KVP, (long)HH * df * KVP, 1, 8, df / 128);
            else
                mfma_nt<64, 128, float><<<dim3(8 * 1 * Z), blk, 0, stream>>>(
                    Qb, KTb, Sb, N, N, KVP, N, scale, 1, 0, 0,
                    (long)df * N, (long)HH * df * N,
                    (long)KVP * N, (long)HH * KVP * N,
                    (long)df * KVP, (long)HH * df * KVP, 1, 8, 1);

            stats_partial_kernel<<<dim3(nchunks, Z), dim3(256), 0, stream>>>(Sb, partialb, df, nchunks);
            stats_final_kernel  <<<dim3(Z), dim3(128), 0, stream>>>(partialb, statsb, df, nchunks);
            softmax_kernel<<<dim3(df, Z), dim3(256), 0, stream>>>(Sb, Sab, statsb, df);

            // Ch[g][h][n][e] = sum_j V[n][j] Sa[e][j]               M=N,Nc=df,K=KVP
            if (df >= 128)
                mfma_nt<128, 128, short><<<dim3((df / 128) * 8 * Z), blk, 0, stream>>>(
                    Vb, Sab, Chb, KVP, KVP, df, KVP, 1.0f, 1, 0, 0,
                    (long)N * KVP, (long)HH * N * KVP,
                    (long)df * KVP, (long)HH * df * KVP,
                    (long)N * df, (long)HH * N * df, 1, df / 128, 8);
            else
                mfma_nt<128, 64, short><<<dim3(1 * 8 * Z), blk, 0, stream>>>(
                    Vb, Sab, Chb, KVP, KVP, df, KVP, 1.0f, 1, 0, 0,
                    (long)N * KVP, (long)HH * N * KVP,
                    (long)df * KVP, (long)HH * df * KVP,
                    (long)N * df, (long)HH * N * df, 1, 1, 8);

            // O[b0+g][n][f] = (1/H) sum_h sum_e Ch[g][h][n][e] WOp[f][e]  M=N,Nc=df,K=df
            if (df >= 128)
                mfma_nt<128, 128, float><<<dim3((df / 128) * 8 * G), blk, 0, stream>>>(
                    Chb, WOp[br], out + outBase[br] + (long)b0 * N * df,
                    df, df, df, df, 1.0f / HH, HH, (long)N * df, 0,
                    0, (long)HH * N * df, 0, 0,
                    0, (long)N * df, 0, df / 128, 8);
            else
                mfma_nt<128, 64, float><<<dim3(1 * 8 * G), blk, 0, stream>>>(
                    Chb, WOp[br], out + outBase[br] + (long)b0 * N * df,
                    df, df, df, df, 1.0f / HH, HH, (long)N * df, 0,
                    0, (long)HH * N * df, 0, 0,
                    0, (long)N * df, 0, 1, 8);
        }
    }
}